// Round 4
// baseline (4720.015 us; speedup 1.0000x reference)
//
#include <hip/hip_runtime.h>
#include <cstddef>

typedef unsigned short bf16;
#define LREL 0.01f

__device__ __forceinline__ float bf2f(unsigned int u) {
    union { unsigned int i; float f; } c; c.i = u << 16; return c.f;
}
__device__ __forceinline__ bf16 f2bf(float f) {
    union { unsigned int i; float f; } c; c.f = f;
    return (bf16)((c.i + 0x7FFFu + ((c.i >> 16) & 1u)) >> 16);   // RNE (finite values)
}
__device__ __forceinline__ unsigned int pack2(float a, float b) {
    return (unsigned int)f2bf(a) | ((unsigned int)f2bf(b) << 16);
}
__device__ __forceinline__ float activate(float v, int ACT) {
    if (ACT == 1) return v > 0.f ? v : 0.f;
    if (ACT == 2) return v > 0.f ? v : LREL * v;
    return v;
}

// C[M,256](bf16) = act(A1@W1 (+ A2@W2) + bias); running-sum epilogue into Cacc (bf16).
// AT = float (in_feat) or bf16 (internal features). GATHER: A1 row r = A1[rows1[r]].
// W fp32 row-major [256][256]; callers pass +256*256 for second half of [512,256] weights.
template<int ACT, bool DUAL, int ACCMODE, bool GATHER, typename AT>
__global__ __launch_bounds__(256) void gemm_k(
    const AT* __restrict__ A1, const int* __restrict__ rows1,
    const bf16* __restrict__ A2,
    const float* __restrict__ W1p, const float* __restrict__ W2p,
    const float* __restrict__ bias,
    bf16* __restrict__ C, bf16* __restrict__ Cacc, int M)
{
    __shared__ float As[16][132];
    __shared__ float Ws[16][132];
    const int tid = threadIdx.x;
    // swizzled 16x16 thread grid: within a wave tx,ty span 0..7 -> <=2-way LDS aliasing
    const int tx = (tid & 7) | ((tid >> 3) & 8);        // b0-2 + b6
    const int ty = ((tid >> 3) & 7) | ((tid >> 4) & 8); // b3-5 + b7
    const int row0 = blockIdx.x * 128;
    const int col0 = blockIdx.y * 128;

    float acc[8][8];
#pragma unroll
    for (int i = 0; i < 8; ++i)
#pragma unroll
        for (int j = 0; j < 8; ++j) acc[i][j] = 0.f;

    const int p   = tid & 1;             // which 8-wide k-chunk this thread stages
    const int a_m = tid >> 1;            // 0..127 (tile row staged)
    const int rr  = min(row0 + a_m, M - 1);
    const size_t aoff1 = (size_t)(GATHER ? rows1[rr] : rr) * 256 + p * 8;
    const size_t aoff2 = (size_t)rr * 256 + p * 8;
    const int w_k = tid >> 5;            // 0..7 (second row at +8)
    const int w_n = (tid & 31) * 4;

    const int nparts = DUAL ? 2 : 1;
    for (int part = 0; part < nparts; ++part) {
        const float* __restrict__ W = (part == 0) ? W1p : W2p;
        for (int kt = 0; kt < 256; kt += 16) {
            float av[8];
            if (part == 0) {
                if constexpr (sizeof(AT) == 4) {
                    const float* ap = (const float*)A1 + aoff1 + kt;
                    float4 f0 = *(const float4*)ap;
                    float4 f1 = *(const float4*)(ap + 4);
                    av[0] = f0.x; av[1] = f0.y; av[2] = f0.z; av[3] = f0.w;
                    av[4] = f1.x; av[5] = f1.y; av[6] = f1.z; av[7] = f1.w;
                } else {
                    uint4 u = *(const uint4*)((const bf16*)A1 + aoff1 + kt);
                    av[0] = bf2f(u.x & 0xFFFFu); av[1] = bf2f(u.x >> 16);
                    av[2] = bf2f(u.y & 0xFFFFu); av[3] = bf2f(u.y >> 16);
                    av[4] = bf2f(u.z & 0xFFFFu); av[5] = bf2f(u.z >> 16);
                    av[6] = bf2f(u.w & 0xFFFFu); av[7] = bf2f(u.w >> 16);
                }
            } else {
                uint4 u = *(const uint4*)(A2 + aoff2 + kt);
                av[0] = bf2f(u.x & 0xFFFFu); av[1] = bf2f(u.x >> 16);
                av[2] = bf2f(u.y & 0xFFFFu); av[3] = bf2f(u.y >> 16);
                av[4] = bf2f(u.z & 0xFFFFu); av[5] = bf2f(u.z >> 16);
                av[6] = bf2f(u.w & 0xFFFFu); av[7] = bf2f(u.w >> 16);
            }
            float4 wv0 = *(const float4*)(W + (size_t)(kt + w_k) * 256 + col0 + w_n);
            float4 wv1 = *(const float4*)(W + (size_t)(kt + w_k + 8) * 256 + col0 + w_n);
            __syncthreads();
#pragma unroll
            for (int j = 0; j < 8; ++j) As[p * 8 + j][a_m] = av[j];
            *(float4*)&Ws[w_k][w_n] = wv0;
            *(float4*)&Ws[w_k + 8][w_n] = wv1;
            __syncthreads();
#pragma unroll
            for (int k = 0; k < 16; ++k) {
                float4 a0 = *(const float4*)&As[k][ty * 8];
                float4 a1 = *(const float4*)&As[k][ty * 8 + 4];
                float4 w0 = *(const float4*)&Ws[k][tx * 8];
                float4 w1 = *(const float4*)&Ws[k][tx * 8 + 4];
                float aa[8] = {a0.x, a0.y, a0.z, a0.w, a1.x, a1.y, a1.z, a1.w};
                float ww[8] = {w0.x, w0.y, w0.z, w0.w, w1.x, w1.y, w1.z, w1.w};
#pragma unroll
                for (int i = 0; i < 8; ++i)
#pragma unroll
                    for (int j = 0; j < 8; ++j)
                        acc[i][j] += aa[i] * ww[j];
            }
        }
    }

#pragma unroll
    for (int i = 0; i < 8; ++i) {
        int r = row0 + ty * 8 + i;
        if (r < M) {
            const int c0 = col0 + tx * 8;
            float o[8];
#pragma unroll
            for (int j = 0; j < 8; ++j) o[j] = activate(acc[i][j] + bias[c0 + j], ACT);
            uint4 cv;
            cv.x = pack2(o[0], o[1]); cv.y = pack2(o[2], o[3]);
            cv.z = pack2(o[4], o[5]); cv.w = pack2(o[6], o[7]);
            *(uint4*)(C + (size_t)r * 256 + c0) = cv;
            if constexpr (ACCMODE == 1) {
                *(uint4*)(Cacc + (size_t)r * 256 + c0) = cv;
            } else if constexpr (ACCMODE == 2) {
                uint4 ov = *(const uint4*)(Cacc + (size_t)r * 256 + c0);
                uint4 nv;
                nv.x = pack2(bf2f(ov.x & 0xFFFFu) + o[0], bf2f(ov.x >> 16) + o[1]);
                nv.y = pack2(bf2f(ov.y & 0xFFFFu) + o[2], bf2f(ov.y >> 16) + o[3]);
                nv.z = pack2(bf2f(ov.z & 0xFFFFu) + o[4], bf2f(ov.z >> 16) + o[5]);
                nv.w = pack2(bf2f(ov.w & 0xFFFFu) + o[6], bf2f(ov.w >> 16) + o[7]);
                *(uint4*)(Cacc + (size_t)r * 256 + c0) = nv;
            }
        }
    }
}

// X1[d] = -re*norm[d]*sum_{e in CSR(d)} x[row(ssrc[e])]*norm[ssrc[e]] + (re-1)*x[row(d)]
// GATHER: row(s)=gidx[s]. One wave per dst row; lane holds 4 of 256 features.
template<bool GATHER>
__global__ void agg_x1(const bf16* __restrict__ x, const int* __restrict__ gidx,
                       const float* __restrict__ norm,
                       const int* __restrict__ rp, const int* __restrict__ ssrc,
                       const float* __restrict__ lam, bf16* __restrict__ X1, int M)
{
    int d = blockIdx.x * 4 + (threadIdx.x >> 6);
    if (d >= M) return;
    int l = threadIdx.x & 63;
    float s0 = 0.f, s1 = 0.f, s2 = 0.f, s3 = 0.f;
    int e0 = rp[d], e1 = rp[d + 1];
    for (int e = e0; e < e1; ++e) {
        int si = ssrc[e];
        float nv = norm[si];
        const bf16* xr = x + (size_t)(GATHER ? gidx[si] : si) * 256 + l * 4;
        uint2 u = *(const uint2*)xr;
        s0 += bf2f(u.x & 0xFFFFu) * nv; s1 += bf2f(u.x >> 16) * nv;
        s2 += bf2f(u.y & 0xFFFFu) * nv; s3 += bf2f(u.y >> 16) * nv;
    }
    float re = 2.0f / lam[0];
    float a = -re * norm[d];
    float b = re - 1.0f;
    const bf16* xdp = x + (size_t)(GATHER ? gidx[d] : d) * 256 + l * 4;
    uint2 xd = *(const uint2*)xdp;
    uint2 o;
    o.x = pack2(a * s0 + b * bf2f(xd.x & 0xFFFFu), a * s1 + b * bf2f(xd.x >> 16));
    o.y = pack2(a * s2 + b * bf2f(xd.y & 0xFFFFu), a * s3 + b * bf2f(xd.y >> 16));
    *(uint2*)(X1 + (size_t)d * 256 + l * 4) = o;
}

__global__ void zero_k(int* __restrict__ p, int n)
{
    int i = blockIdx.x * 256 + threadIdx.x;
    if (i < n) p[i] = 0;
}

__global__ void hist_k(const int* __restrict__ dst, int* __restrict__ deg, int E)
{
    int e = blockIdx.x * 256 + threadIdx.x;
    if (e < E) atomicAdd(&deg[dst[e]], 1);
}

// single-block 256-thread exclusive scan of deg[0..M) -> rp[0..M] (LDS Hillis-Steele)
__global__ void scan_k(const int* __restrict__ deg, int* __restrict__ rp, int M)
{
    __shared__ int buf[256];
    __shared__ int carry;
    const int t = threadIdx.x;
    if (t == 0) carry = 0;
    __syncthreads();
    for (int base = 0; base < M; base += 256) {
        int v = (base + t < M) ? deg[base + t] : 0;
        buf[t] = v;
        __syncthreads();
        for (int off = 1; off < 256; off <<= 1) {
            int y = (t >= off) ? buf[t - off] : 0;
            __syncthreads();
            buf[t] += y;
            __syncthreads();
        }
        int c = carry;
        if (base + t < M) rp[base + t] = c + buf[t] - v;
        __syncthreads();
        if (t == 0) carry = c + buf[255];
        __syncthreads();
    }
    if (t == 0) rp[M] = carry;
}

__global__ void scatter_k(const int* __restrict__ src, const int* __restrict__ dst,
                          const int* __restrict__ rp, int* __restrict__ cursor,
                          int* __restrict__ out, int E)
{
    int e = blockIdx.x * 256 + threadIdx.x;
    if (e < E) {
        int d = dst[e];
        int pos = rp[d] + atomicAdd(&cursor[d], 1);
        out[pos] = src[e];
    }
}

// out[r,0:2] = leaky_relu(ACC[r,:]) @ W4 + b4 ; one wave per row
__global__ void final_k(const bf16* __restrict__ acc, const float* __restrict__ W4,
                        const float* __restrict__ b4, float* __restrict__ out, int Nn)
{
    int r = blockIdx.x * 4 + (threadIdx.x >> 6);
    if (r >= Nn) return;
    int l = threadIdx.x & 63;
    uint2 u = *(const uint2*)(acc + (size_t)r * 256 + l * 4);
    float v[4] = { bf2f(u.x & 0xFFFFu), bf2f(u.x >> 16),
                   bf2f(u.y & 0xFFFFu), bf2f(u.y >> 16) };
    float s0 = 0.f, s1 = 0.f;
#pragma unroll
    for (int j = 0; j < 4; ++j) {
        float x = v[j] > 0.f ? v[j] : LREL * v[j];
        int k = l * 4 + j;
        s0 += x * W4[k * 2 + 0];
        s1 += x * W4[k * 2 + 1];
    }
#pragma unroll
    for (int off = 32; off; off >>= 1) {
        s0 += __shfl_xor(s0, off, 64);
        s1 += __shfl_xor(s1, off, 64);
    }
    if (l == 0) {
        out[(size_t)r * 2 + 0] = s0 + b4[0];
        out[(size_t)r * 2 + 1] = s1 + b4[1];
    }
}

extern "C" void kernel_launch(void* const* d_in, const int* in_sizes, int n_in,
                              void* d_out, int out_size, void* d_ws, size_t ws_size,
                              hipStream_t stream)
{
    const float* in_feat = (const float*)d_in[0];
    const int Nn = in_sizes[0] / 256;   // 100000

    const float* W_lin = (const float*)d_in[19]; const float* b_lin = (const float*)d_in[20];
    const float* W2p   = (const float*)d_in[21]; const float* b2   = (const float*)d_in[22];
    const float* W1sg  = (const float*)d_in[23]; const float* b1sg = (const float*)d_in[24];
    const float* W2sg  = (const float*)d_in[25]; const float* b2sg = (const float*)d_in[26];
    const float* Wc1   = (const float*)d_in[27]; const float* bc1  = (const float*)d_in[28];
    const float* Wc2   = (const float*)d_in[29]; const float* bc2  = (const float*)d_in[30];
    const float* W3p   = (const float*)d_in[31]; const float* b3   = (const float*)d_in[32];
    const float* W4p   = (const float*)d_in[33]; const float* b4   = (const float*)d_in[34];

    int Mr[3], NIr[3], Er[3];
    int M_max = 0, NI_max = 0, E_max = 0;
    for (int r = 0; r < 3; ++r) {
        Mr[r]  = in_sizes[1 + 6 * r];
        NIr[r] = in_sizes[2 + 6 * r];
        Er[r]  = in_sizes[3 + 6 * r];
        if (Mr[r] > M_max)  M_max  = Mr[r];
        if (NIr[r] > NI_max) NI_max = NIr[r];
        if (Er[r] > E_max)  E_max  = Er[r];
    }

    // workspace (bf16 features): ~243 MB total for this problem
    bf16* ACC = (bf16*)d_ws;                         // [Nn,256] running sum (tmp for layer0)
    bf16* H   = ACC + (size_t)Nn * 256;              // [Nn,256] current node features
    bf16* S1  = H + (size_t)Nn * 256;                // [M_max,256] X1 / h02
    bf16* S2  = S1 + (size_t)M_max * 256;            // [M_max,256] h01
    bf16* S3  = S2 + (size_t)M_max * 256;            // [M_max,256] h11
    bf16* S4  = S3 + (size_t)M_max * 256;            // [NI_max,256] h12
    int* deg    = (int*)(S4 + (size_t)NI_max * 256); // [Nn+1]
    int* cursor = deg + (Nn + 1);                    // [Nn+1]
    int* rp     = cursor + (Nn + 1);                 // [Nn+1]
    int* ssrc   = rp + (Nn + 1);                     // [E_max]

    auto g2 = [](int M) { return dim3((unsigned)((M + 127) / 128), 2); };
    const size_t HOFF = 256 * 256;                   // second half of a [512,256] weight

    // h = leaky(leaky(in @ W_lin + b_lin) @ W2 + b2)
    gemm_k<2, false, 0, false, float><<<g2(Nn), 256, 0, stream>>>(
        in_feat, nullptr, nullptr, W_lin, nullptr, b_lin, ACC, nullptr, Nn);
    gemm_k<2, false, 0, false, bf16><<<g2(Nn), 256, 0, stream>>>(
        ACC, nullptr, nullptr, W2p, nullptr, b2, H, nullptr, Nn);

    for (int r = 0; r < 3; ++r) {
        const int*   keep = (const int*)d_in[1 + 6 * r];
        const int*   iso  = (const int*)d_in[2 + 6 * r];
        const int*   srcA = (const int*)d_in[3 + 6 * r];
        const int*   dstA = (const int*)d_in[4 + 6 * r];
        const float* norm = (const float*)d_in[5 + 6 * r];
        const float* lam  = (const float*)d_in[6 + 6 * r];
        const int M  = Mr[r];
        const int NI = NIr[r];
        const int E  = Er[r];

        // build CSR (src ids grouped by dst) for this relation
        zero_k<<<(2 * (Nn + 1) + 255) / 256, 256, 0, stream>>>(deg, 2 * (Nn + 1));
        hist_k<<<(E + 255) / 256, 256, 0, stream>>>(dstA, deg, E);
        scan_k<<<1, 256, 0, stream>>>(deg, rp, M);
        scatter_k<<<(E + 255) / 256, 256, 0, stream>>>(srcA, dstA, rp, cursor, ssrc, E);

        // cheb1: h01 = relu([H[keep], X1] @ Wc1 + bc1)
        agg_x1<true><<<(M + 3) / 4, 256, 0, stream>>>(H, keep, norm, rp, ssrc, lam, S1, M);
        gemm_k<1, true, 0, true, bf16><<<g2(M), 256, 0, stream>>>(
            H, keep, S1, Wc1, Wc1 + HOFF, bc1, S2, nullptr, M);
        // cheb2: h11 = relu([h01, X1'] @ Wc2 + bc2)
        agg_x1<false><<<(M + 3) / 4, 256, 0, stream>>>(S2, nullptr, norm, rp, ssrc, lam, S1, M);
        gemm_k<1, true, 0, false, bf16><<<g2(M), 256, 0, stream>>>(
            S2, nullptr, S1, Wc2, Wc2 + HOFF, bc2, S3, nullptr, M);

        // iso branch: h02 = H[iso]@W1sg + b1sg ; h12 = h02@W2sg + b2sg
        gemm_k<0, false, 0, true, bf16><<<g2(NI), 256, 0, stream>>>(
            H, iso, nullptr, W1sg, nullptr, b1sg, S1, nullptr, NI);
        gemm_k<0, false, 0, false, bf16><<<g2(NI), 256, 0, stream>>>(
            S1, nullptr, nullptr, W2sg, nullptr, b2sg, S4, nullptr, NI);

        // block output overwrites H; running sum into ACC (init on r==0)
        if (r == 0) {
            gemm_k<0, true, 1, false, bf16><<<g2(NI), 256, 0, stream>>>(
                S1, nullptr, S4, W3p, W3p + HOFF, b3,
                H + (size_t)M * 256, ACC + (size_t)M * 256, NI);
            gemm_k<0, true, 1, false, bf16><<<g2(M), 256, 0, stream>>>(
                S2, nullptr, S3, W3p, W3p + HOFF, b3, H, ACC, M);
        } else {
            gemm_k<0, true, 2, false, bf16><<<g2(NI), 256, 0, stream>>>(
                S1, nullptr, S4, W3p, W3p + HOFF, b3,
                H + (size_t)M * 256, ACC + (size_t)M * 256, NI);
            gemm_k<0, true, 2, false, bf16><<<g2(M), 256, 0, stream>>>(
                S2, nullptr, S3, W3p, W3p + HOFF, b3, H, ACC, M);
        }
    }

    final_k<<<(Nn + 3) / 4, 256, 0, stream>>>(ACC, W4p, b4, (float*)d_out, Nn);
}

// Round 5
// 2618.518 us; speedup vs baseline: 1.8026x; 1.8026x over previous
//
#include <hip/hip_runtime.h>
#include <cstddef>

typedef unsigned short bf16;
typedef short bf16x8 __attribute__((ext_vector_type(8)));
typedef float f32x4 __attribute__((ext_vector_type(4)));
#define LREL 0.01f

__device__ __forceinline__ float bf2f(unsigned int u) {
    union { unsigned int i; float f; } c; c.i = u << 16; return c.f;
}
__device__ __forceinline__ bf16 f2bf(float f) {
    union { unsigned int i; float f; } c; c.f = f;
    return (bf16)((c.i + 0x7FFFu + ((c.i >> 16) & 1u)) >> 16);   // RNE (finite)
}
__device__ __forceinline__ unsigned int pack2(float a, float b) {
    return (unsigned int)f2bf(a) | ((unsigned int)f2bf(b) << 16);
}
__device__ __forceinline__ float activate(float v, int ACT) {
    if (ACT == 1) return v > 0.f ? v : 0.f;
    if (ACT == 2) return v > 0.f ? v : LREL * v;
    return v;
}

// ---------------- MFMA GEMM ----------------
// C[M,256](bf16) = act(A1@W1 (+ A2@W2) + bias); optional running-sum into Cacc.
// A: bf16 [*,256] (or fp32 when AFP32, layer-0 only). WT*: bf16 [256 n][256 k]
// (transposed weights). GATHER: A1 row r = A1[rows1[r]]. 128x128 tile, BK=64,
// 4 waves (2x2), v_mfma_f32_16x16x32_bf16, fp32 accum.
// LDS chunk swizzle: 16B chunk c of row r stored at slot c^(r&7)  (kills the
// 128B-row-stride 16-way bank conflict; same XOR on write and read).
template<int ACT, bool DUAL, int ACCMODE, bool GATHER, bool AFP32>
__global__ __launch_bounds__(256) void gemm_mfma(
    const void* __restrict__ A1v, const int* __restrict__ rows1,
    const bf16* __restrict__ A2,
    const bf16* __restrict__ WT1, const bf16* __restrict__ WT2,
    const float* __restrict__ bias,
    bf16* __restrict__ C, bf16* __restrict__ Cacc, int M)
{
    __shared__ bf16 As[128 * 64];
    __shared__ bf16 Bs[128 * 64];
    const int tid  = threadIdx.x;
    const int lane = tid & 63;
    const int wv   = tid >> 6;           // wave 0..3
    const int wr   = wv >> 1, wc = wv & 1;
    const int row0 = blockIdx.x * 128;
    const int col0 = blockIdx.y * 128;

    f32x4 acc[4][4];
#pragma unroll
    for (int mi = 0; mi < 4; ++mi)
#pragma unroll
        for (int ni = 0; ni < 4; ++ni)
#pragma unroll
            for (int e = 0; e < 4; ++e) acc[mi][ni][e] = 0.f;

    // staging: thread stages A row (tid&127) / B col (tid&127), k-half (tid>>7)
    const int ar = tid & 127;
    const int kh = tid >> 7;             // 0/1 -> chunks kh*4..kh*4+3 (16B each)
    const int arow = min(row0 + ar, M - 1);
    const size_t aoff1 = (size_t)(GATHER ? rows1[arow] : arow) * 256;
    const size_t aoff2 = (size_t)arow * 256;
    const int bn = ar;

    const int nparts = DUAL ? 2 : 1;
    for (int part = 0; part < nparts; ++part) {
        const bf16* __restrict__ WT = (part == 0) ? WT1 : WT2;
        for (int kt = 0; kt < 256; kt += 64) {
            uint4 areg[4], breg[4];
#pragma unroll
            for (int cc = 0; cc < 4; ++cc) {
                const int c = kh * 4 + cc;
                if (part == 0) {
                    if constexpr (AFP32) {
                        const float* p = (const float*)A1v + aoff1 + kt + c * 8;
                        float4 f0 = *(const float4*)p;
                        float4 f1 = *(const float4*)(p + 4);
                        areg[cc].x = pack2(f0.x, f0.y); areg[cc].y = pack2(f0.z, f0.w);
                        areg[cc].z = pack2(f1.x, f1.y); areg[cc].w = pack2(f1.z, f1.w);
                    } else {
                        areg[cc] = *(const uint4*)((const bf16*)A1v + aoff1 + kt + c * 8);
                    }
                } else {
                    areg[cc] = *(const uint4*)(A2 + aoff2 + kt + c * 8);
                }
                breg[cc] = *(const uint4*)(WT + (size_t)(col0 + bn) * 256 + kt + c * 8);
            }
            __syncthreads();            // previous compute done before overwrite
#pragma unroll
            for (int cc = 0; cc < 4; ++cc) {
                const int c = kh * 4 + cc;
                *(uint4*)(As + ar * 64 + 8 * (c ^ (ar & 7))) = areg[cc];
                *(uint4*)(Bs + bn * 64 + 8 * (c ^ (bn & 7))) = breg[cc];
            }
            __syncthreads();
#pragma unroll
            for (int ks = 0; ks < 2; ++ks) {
                bf16x8 af[4], bfr[4];
#pragma unroll
                for (int mi = 0; mi < 4; ++mi) {
                    const int r = wr * 64 + mi * 16 + (lane & 15);
                    const int c = ks * 4 + (lane >> 4);
                    af[mi] = *(const bf16x8*)(As + r * 64 + 8 * (c ^ (r & 7)));
                }
#pragma unroll
                for (int ni = 0; ni < 4; ++ni) {
                    const int n = wc * 64 + ni * 16 + (lane & 15);
                    const int c = ks * 4 + (lane >> 4);
                    bfr[ni] = *(const bf16x8*)(Bs + n * 64 + 8 * (c ^ (n & 7)));
                }
#pragma unroll
                for (int mi = 0; mi < 4; ++mi)
#pragma unroll
                    for (int ni = 0; ni < 4; ++ni)
                        acc[mi][ni] = __builtin_amdgcn_mfma_f32_16x16x32_bf16(
                            af[mi], bfr[ni], acc[mi][ni], 0, 0, 0);
            }
        }
    }

    // epilogue: D row = (lane>>4)*4+reg, col = lane&15  [m89-verified layout]
#pragma unroll
    for (int mi = 0; mi < 4; ++mi) {
#pragma unroll
        for (int reg = 0; reg < 4; ++reg) {
            const int r = row0 + wr * 64 + mi * 16 + (lane >> 4) * 4 + reg;
            if (r < M) {
#pragma unroll
                for (int ni = 0; ni < 4; ++ni) {
                    const int cx = col0 + wc * 64 + ni * 16 + (lane & 15);
                    float v = activate(acc[mi][ni][reg] + bias[cx], ACT);
                    C[(size_t)r * 256 + cx] = f2bf(v);
                    if constexpr (ACCMODE == 1) {
                        Cacc[(size_t)r * 256 + cx] = f2bf(v);
                    } else if constexpr (ACCMODE == 2) {
                        float o = bf2f(Cacc[(size_t)r * 256 + cx]);
                        Cacc[(size_t)r * 256 + cx] = f2bf(o + v);
                    }
                }
            }
        }
    }
}

// convert 10x [256][256] fp32 weight blocks -> bf16 transposed [n][k]
__global__ void wconv_all(const float* __restrict__ W_lin, const float* __restrict__ W2,
                          const float* __restrict__ W1sg, const float* __restrict__ W2sg,
                          const float* __restrict__ Wc1, const float* __restrict__ Wc2,
                          const float* __restrict__ W3, bf16* __restrict__ out)
{
    const int b = blockIdx.x;
    const int m = b >> 8, k = b & 255, n = threadIdx.x;
    const float* src;
    switch (m) {
        case 0: src = W_lin; break;       case 1: src = W2; break;
        case 2: src = W1sg; break;        case 3: src = W2sg; break;
        case 4: src = Wc1; break;         case 5: src = Wc1 + 65536; break;
        case 6: src = Wc2; break;         case 7: src = Wc2 + 65536; break;
        case 8: src = W3; break;          default: src = W3 + 65536; break;
    }
    out[(size_t)m * 65536 + n * 256 + k] = f2bf(src[k * 256 + n]);
}

// ---------------- graph aggregation ----------------
template<bool GATHER>
__global__ void agg_x1(const bf16* __restrict__ x, const int* __restrict__ gidx,
                       const float* __restrict__ norm,
                       const int* __restrict__ rp, const int* __restrict__ ssrc,
                       const float* __restrict__ lam, bf16* __restrict__ X1, int M)
{
    int d = blockIdx.x * 4 + (threadIdx.x >> 6);
    if (d >= M) return;
    int l = threadIdx.x & 63;
    float s0 = 0.f, s1 = 0.f, s2 = 0.f, s3 = 0.f;
    int e0 = rp[d], e1 = rp[d + 1];
    for (int e = e0; e < e1; ++e) {
        int si = ssrc[e];
        float nv = norm[si];
        const bf16* xr = x + (size_t)(GATHER ? gidx[si] : si) * 256 + l * 4;
        uint2 u = *(const uint2*)xr;
        s0 += bf2f(u.x & 0xFFFFu) * nv; s1 += bf2f(u.x >> 16) * nv;
        s2 += bf2f(u.y & 0xFFFFu) * nv; s3 += bf2f(u.y >> 16) * nv;
    }
    float re = 2.0f / lam[0];
    float a = -re * norm[d];
    float b = re - 1.0f;
    const bf16* xdp = x + (size_t)(GATHER ? gidx[d] : d) * 256 + l * 4;
    uint2 xd = *(const uint2*)xdp;
    uint2 o;
    o.x = pack2(a * s0 + b * bf2f(xd.x & 0xFFFFu), a * s1 + b * bf2f(xd.x >> 16));
    o.y = pack2(a * s2 + b * bf2f(xd.y & 0xFFFFu), a * s3 + b * bf2f(xd.y >> 16));
    *(uint2*)(X1 + (size_t)d * 256 + l * 4) = o;
}

__global__ void zero_k(int* __restrict__ p, int n)
{
    int i = blockIdx.x * 256 + threadIdx.x;
    if (i < n) p[i] = 0;
}

__global__ void hist_k(const int* __restrict__ dst, int* __restrict__ deg, int E)
{
    int e = blockIdx.x * 256 + threadIdx.x;
    if (e < E) atomicAdd(&deg[dst[e]], 1);
}

// ---- parallel 3-phase exclusive scan: deg[0..M) -> rp[0..M] ----
__global__ void scan1_k(const int* __restrict__ deg, int* __restrict__ bsum, int M)
{
    __shared__ int red[256];
    int b = blockIdx.x, t = threadIdx.x;
    int base = b * 1024 + t * 4;
    int s = 0;
#pragma unroll
    for (int j = 0; j < 4; ++j) { int i = base + j; if (i < M) s += deg[i]; }
    red[t] = s; __syncthreads();
    for (int off = 128; off; off >>= 1) {
        if (t < off) red[t] += red[t + off];
        __syncthreads();
    }
    if (t == 0) bsum[b] = red[0];
}
__global__ void scan2_k(int* __restrict__ bsum, int nb, int* __restrict__ rp, int M)
{
    __shared__ int buf[256];
    int t = threadIdx.x;
    int v = (t < nb) ? bsum[t] : 0;
    buf[t] = v; __syncthreads();
    for (int off = 1; off < 256; off <<= 1) {
        int y = (t >= off) ? buf[t - off] : 0;
        __syncthreads();
        buf[t] += y;
        __syncthreads();
    }
    if (t < nb) bsum[t] = buf[t] - v;       // exclusive prefix of block sums
    if (t == 0) rp[M] = buf[255];           // total
}
__global__ void scan3_k(const int* __restrict__ deg, const int* __restrict__ bsum,
                        int* __restrict__ rp, int M)
{
    __shared__ int buf[256];
    int b = blockIdx.x, t = threadIdx.x;
    int base = b * 1024 + t * 4;
    int v0 = (base + 0 < M) ? deg[base + 0] : 0;
    int v1 = (base + 1 < M) ? deg[base + 1] : 0;
    int v2 = (base + 2 < M) ? deg[base + 2] : 0;
    int v3 = (base + 3 < M) ? deg[base + 3] : 0;
    int s = v0 + v1 + v2 + v3;
    buf[t] = s; __syncthreads();
    for (int off = 1; off < 256; off <<= 1) {
        int y = (t >= off) ? buf[t - off] : 0;
        __syncthreads();
        buf[t] += y;
        __syncthreads();
    }
    int ex = bsum[b] + buf[t] - s;
    if (base + 0 < M) rp[base + 0] = ex;
    if (base + 1 < M) rp[base + 1] = ex + v0;
    if (base + 2 < M) rp[base + 2] = ex + v0 + v1;
    if (base + 3 < M) rp[base + 3] = ex + v0 + v1 + v2;
}

__global__ void scatter_k(const int* __restrict__ src, const int* __restrict__ dst,
                          const int* __restrict__ rp, int* __restrict__ cursor,
                          int* __restrict__ out, int E)
{
    int e = blockIdx.x * 256 + threadIdx.x;
    if (e < E) {
        int d = dst[e];
        int pos = rp[d] + atomicAdd(&cursor[d], 1);
        out[pos] = src[e];
    }
}

// out[r,0:2] = leaky_relu(ACC[r,:]) @ W4 + b4 ; one wave per row
__global__ void final_k(const bf16* __restrict__ acc, const float* __restrict__ W4,
                        const float* __restrict__ b4, float* __restrict__ out, int Nn)
{
    int r = blockIdx.x * 4 + (threadIdx.x >> 6);
    if (r >= Nn) return;
    int l = threadIdx.x & 63;
    uint2 u = *(const uint2*)(acc + (size_t)r * 256 + l * 4);
    float v[4] = { bf2f(u.x & 0xFFFFu), bf2f(u.x >> 16),
                   bf2f(u.y & 0xFFFFu), bf2f(u.y >> 16) };
    float s0 = 0.f, s1 = 0.f;
#pragma unroll
    for (int j = 0; j < 4; ++j) {
        float x = v[j] > 0.f ? v[j] : LREL * v[j];
        int k = l * 4 + j;
        s0 += x * W4[k * 2 + 0];
        s1 += x * W4[k * 2 + 1];
    }
#pragma unroll
    for (int off = 32; off; off >>= 1) {
        s0 += __shfl_xor(s0, off, 64);
        s1 += __shfl_xor(s1, off, 64);
    }
    if (l == 0) {
        out[(size_t)r * 2 + 0] = s0 + b4[0];
        out[(size_t)r * 2 + 1] = s1 + b4[1];
    }
}

extern "C" void kernel_launch(void* const* d_in, const int* in_sizes, int n_in,
                              void* d_out, int out_size, void* d_ws, size_t ws_size,
                              hipStream_t stream)
{
    const float* in_feat = (const float*)d_in[0];
    const int Nn = in_sizes[0] / 256;   // 100000

    const float* W_lin = (const float*)d_in[19]; const float* b_lin = (const float*)d_in[20];
    const float* W2p   = (const float*)d_in[21]; const float* b2   = (const float*)d_in[22];
    const float* W1sg  = (const float*)d_in[23]; const float* b1sg = (const float*)d_in[24];
    const float* W2sg  = (const float*)d_in[25]; const float* b2sg = (const float*)d_in[26];
    const float* Wc1   = (const float*)d_in[27]; const float* bc1  = (const float*)d_in[28];
    const float* Wc2   = (const float*)d_in[29]; const float* bc2  = (const float*)d_in[30];
    const float* W3p   = (const float*)d_in[31]; const float* b3   = (const float*)d_in[32];
    const float* W4p   = (const float*)d_in[33]; const float* b4   = (const float*)d_in[34];

    int Mr[3], NIr[3], Er[3];
    int M_max = 0, NI_max = 0, E_max = 0;
    for (int r = 0; r < 3; ++r) {
        Mr[r]  = in_sizes[1 + 6 * r];
        NIr[r] = in_sizes[2 + 6 * r];
        Er[r]  = in_sizes[3 + 6 * r];
        if (Mr[r] > M_max)  M_max  = Mr[r];
        if (NIr[r] > NI_max) NI_max = NIr[r];
        if (Er[r] > E_max)  E_max  = Er[r];
    }

    // workspace (bf16 features), ~245 MB
    bf16* ACC = (bf16*)d_ws;                         // [Nn,256] running sum (tmp for layer0)
    bf16* H   = ACC + (size_t)Nn * 256;              // [Nn,256] current features
    bf16* S1  = H + (size_t)Nn * 256;                // [M_max,256] X1 / h02
    bf16* S2  = S1 + (size_t)M_max * 256;            // [M_max,256] h01
    bf16* S3  = S2 + (size_t)M_max * 256;            // [M_max,256] h11
    bf16* S4  = S3 + (size_t)M_max * 256;            // [NI_max,256] h12
    bf16* WTb = S4 + (size_t)NI_max * 256;           // 10 x [256][256] bf16 transposed
    int* deg    = (int*)(WTb + 10 * 65536);          // [Nn+1]
    int* cursor = deg + (Nn + 1);                    // [Nn+1]
    int* rp     = cursor + (Nn + 1);                 // [Nn+1]
    int* bsum   = rp + (Nn + 1);                     // [256]
    int* ssrc   = bsum + 256;                        // [E_max]

    bf16* WT_lin = WTb;             bf16* WT_2   = WTb + 1 * 65536;
    bf16* WT_1sg = WTb + 2 * 65536; bf16* WT_2sg = WTb + 3 * 65536;
    bf16* WT_c1a = WTb + 4 * 65536; bf16* WT_c1b = WTb + 5 * 65536;
    bf16* WT_c2a = WTb + 6 * 65536; bf16* WT_c2b = WTb + 7 * 65536;
    bf16* WT_3a  = WTb + 8 * 65536; bf16* WT_3b  = WTb + 9 * 65536;

    auto g2 = [](int M) { return dim3((unsigned)((M + 127) / 128), 2); };

    // weights -> bf16 transposed (graph-safe, every call)
    wconv_all<<<2560, 256, 0, stream>>>(W_lin, W2p, W1sg, W2sg, Wc1, Wc2, W3p, WTb);

    // h = leaky(leaky(in @ W_lin + b_lin) @ W2 + b2)
    gemm_mfma<2, false, 0, false, true><<<g2(Nn), 256, 0, stream>>>(
        in_feat, nullptr, nullptr, WT_lin, nullptr, b_lin, ACC, nullptr, Nn);
    gemm_mfma<2, false, 0, false, false><<<g2(Nn), 256, 0, stream>>>(
        ACC, nullptr, nullptr, WT_2, nullptr, b2, H, nullptr, Nn);

    for (int r = 0; r < 3; ++r) {
        const int*   keep = (const int*)d_in[1 + 6 * r];
        const int*   iso  = (const int*)d_in[2 + 6 * r];
        const int*   srcA = (const int*)d_in[3 + 6 * r];
        const int*   dstA = (const int*)d_in[4 + 6 * r];
        const float* norm = (const float*)d_in[5 + 6 * r];
        const float* lam  = (const float*)d_in[6 + 6 * r];
        const int M  = Mr[r];
        const int NI = NIr[r];
        const int E  = Er[r];
        const int nb = (M + 1023) / 1024;

        // CSR build (src ids grouped by dst)
        zero_k<<<(2 * (Nn + 1) + 255) / 256, 256, 0, stream>>>(deg, 2 * (Nn + 1));
        hist_k<<<(E + 255) / 256, 256, 0, stream>>>(dstA, deg, E);
        scan1_k<<<nb, 256, 0, stream>>>(deg, bsum, M);
        scan2_k<<<1, 256, 0, stream>>>(bsum, nb, rp, M);
        scan3_k<<<nb, 256, 0, stream>>>(deg, bsum, rp, M);
        scatter_k<<<(E + 255) / 256, 256, 0, stream>>>(srcA, dstA, rp, cursor, ssrc, E);

        // cheb1: h01 = relu([H[keep], X1] @ Wc1 + bc1)
        agg_x1<true><<<(M + 3) / 4, 256, 0, stream>>>(H, keep, norm, rp, ssrc, lam, S1, M);
        gemm_mfma<1, true, 0, true, false><<<g2(M), 256, 0, stream>>>(
            H, keep, S1, WT_c1a, WT_c1b, bc1, S2, nullptr, M);
        // cheb2: h11 = relu([h01, X1'] @ Wc2 + bc2)
        agg_x1<false><<<(M + 3) / 4, 256, 0, stream>>>(S2, nullptr, norm, rp, ssrc, lam, S1, M);
        gemm_mfma<1, true, 0, false, false><<<g2(M), 256, 0, stream>>>(
            S2, nullptr, S1, WT_c2a, WT_c2b, bc2, S3, nullptr, M);

        // iso branch: h02 = H[iso]@W1sg + b1sg ; h12 = h02@W2sg + b2sg
        gemm_mfma<0, false, 0, true, false><<<g2(NI), 256, 0, stream>>>(
            H, iso, nullptr, WT_1sg, nullptr, b1sg, S1, nullptr, NI);
        gemm_mfma<0, false, 0, false, false><<<g2(NI), 256, 0, stream>>>(
            S1, nullptr, nullptr, WT_2sg, nullptr, b2sg, S4, nullptr, NI);

        // block output overwrites H (iso rows first; all old-H reads are done)
        if (r == 0) {
            gemm_mfma<0, true, 1, false, false><<<g2(NI), 256, 0, stream>>>(
                S1, nullptr, S4, WT_3a, WT_3b, b3,
                H + (size_t)M * 256, ACC + (size_t)M * 256, NI);
            gemm_mfma<0, true, 1, false, false><<<g2(M), 256, 0, stream>>>(
                S2, nullptr, S3, WT_3a, WT_3b, b3, H, ACC, M);
        } else {
            gemm_mfma<0, true, 2, false, false><<<g2(NI), 256, 0, stream>>>(
                S1, nullptr, S4, WT_3a, WT_3b, b3,
                H + (size_t)M * 256, ACC + (size_t)M * 256, NI);
            gemm_mfma<0, true, 2, false, false><<<g2(M), 256, 0, stream>>>(
                S2, nullptr, S3, WT_3a, WT_3b, b3, H, ACC, M);
        }
    }

    final_k<<<(Nn + 3) / 4, 256, 0, stream>>>(ACC, W4p, b4, (float*)d_out, Nn);
}

// Round 7
// 2576.097 us; speedup vs baseline: 1.8322x; 1.0165x over previous
//
#include <hip/hip_runtime.h>
#include <cstddef>

typedef unsigned short bf16;
typedef short bf16x8 __attribute__((ext_vector_type(8)));
typedef float f32x4 __attribute__((ext_vector_type(4)));
#define LREL 0.01f

__device__ __forceinline__ float bf2f(unsigned int u) {
    union { unsigned int i; float f; } c; c.i = u << 16; return c.f;
}
__device__ __forceinline__ bf16 f2bf(float f) {
    union { unsigned int i; float f; } c; c.f = f;
    return (bf16)((c.i + 0x7FFFu + ((c.i >> 16) & 1u)) >> 16);   // RNE (finite)
}
__device__ __forceinline__ unsigned int pack2(float a, float b) {
    return (unsigned int)f2bf(a) | ((unsigned int)f2bf(b) << 16);
}
__device__ __forceinline__ float activate(float v, int ACT) {
    if (ACT == 1) return v > 0.f ? v : 0.f;
    if (ACT == 2) return v > 0.f ? v : LREL * v;
    return v;
}

// ---------------- MFMA GEMM ----------------
// C[M,256](bf16) = act(A1@W1 (+ A2@W2) + bias); optional running-sum into Cacc.
// A: bf16 [*,256] (or fp32 when AFP32, layer-0 only). WT*: bf16 [256 n][256 k]
// (transposed weights). GATHER: A1 row r = A1[rows1[r]]. 128x128 tile, BK=64,
// 4 waves (2x2), v_mfma_f32_16x16x32_bf16 with SWAPPED operands:
// mfma(B,A) -> D[n][m], lane layout: m = lane&15, n = (lane>>4)*4+reg.
// Each lane thus owns 4 CONSECUTIVE cols of one row -> 8B coalesced stores
// (fixes the 7x write amplification seen in R5: 2B scattered stores -> 354MB
// WRITE_SIZE vs 51MB ideal).
// LDS chunk swizzle: 16B chunk c of row r stored at slot c^(r&7).
// grid = (2 col-tiles, row-tiles): the 2 blocks sharing an A-tile are
// dispatch-adjacent -> A re-read hits L2.
template<int ACT, bool DUAL, int ACCMODE, bool GATHER, bool AFP32>
__global__ __launch_bounds__(256) void gemm_mfma(
    const void* __restrict__ A1v, const int* __restrict__ rows1,
    const bf16* __restrict__ A2,
    const bf16* __restrict__ WT1, const bf16* __restrict__ WT2,
    const float* __restrict__ bias,
    bf16* __restrict__ C, bf16* __restrict__ Cacc, int M)
{
    __shared__ bf16 As[128 * 64];
    __shared__ bf16 Bs[128 * 64];
    const int tid  = threadIdx.x;
    const int lane = tid & 63;
    const int wv   = tid >> 6;           // wave 0..3
    const int wr   = wv >> 1, wc = wv & 1;
    const int row0 = blockIdx.y * 128;
    const int col0 = blockIdx.x * 128;

    f32x4 acc[4][4];
#pragma unroll
    for (int mi = 0; mi < 4; ++mi)
#pragma unroll
        for (int ni = 0; ni < 4; ++ni)
#pragma unroll
            for (int e = 0; e < 4; ++e) acc[mi][ni][e] = 0.f;

    // staging: thread stages A row (tid&127) / B col (tid&127), k-half (tid>>7)
    const int ar = tid & 127;
    const int kh = tid >> 7;             // 0/1 -> chunks kh*4..kh*4+3 (16B each)
    const int arow = min(row0 + ar, M - 1);
    const size_t aoff1 = (size_t)(GATHER ? rows1[arow] : arow) * 256;
    const size_t aoff2 = (size_t)arow * 256;
    const int bn = ar;

    const int nparts = DUAL ? 2 : 1;
    for (int part = 0; part < nparts; ++part) {
        const bf16* __restrict__ WT = (part == 0) ? WT1 : WT2;
        for (int kt = 0; kt < 256; kt += 64) {
            uint4 areg[4], breg[4];
#pragma unroll
            for (int cc = 0; cc < 4; ++cc) {
                const int c = kh * 4 + cc;
                if (part == 0) {
                    if constexpr (AFP32) {
                        const float* p = (const float*)A1v + aoff1 + kt + c * 8;
                        float4 f0 = *(const float4*)p;
                        float4 f1 = *(const float4*)(p + 4);
                        areg[cc].x = pack2(f0.x, f0.y); areg[cc].y = pack2(f0.z, f0.w);
                        areg[cc].z = pack2(f1.x, f1.y); areg[cc].w = pack2(f1.z, f1.w);
                    } else {
                        areg[cc] = *(const uint4*)((const bf16*)A1v + aoff1 + kt + c * 8);
                    }
                } else {
                    areg[cc] = *(const uint4*)(A2 + aoff2 + kt + c * 8);
                }
                breg[cc] = *(const uint4*)(WT + (size_t)(col0 + bn) * 256 + kt + c * 8);
            }
            __syncthreads();            // previous compute done before overwrite
#pragma unroll
            for (int cc = 0; cc < 4; ++cc) {
                const int c = kh * 4 + cc;
                *(uint4*)(As + ar * 64 + 8 * (c ^ (ar & 7))) = areg[cc];
                *(uint4*)(Bs + bn * 64 + 8 * (c ^ (bn & 7))) = breg[cc];
            }
            __syncthreads();
#pragma unroll
            for (int ks = 0; ks < 2; ++ks) {
                bf16x8 af[4], bfr[4];
#pragma unroll
                for (int mi = 0; mi < 4; ++mi) {
                    const int r = wr * 64 + mi * 16 + (lane & 15);
                    const int c = ks * 4 + (lane >> 4);
                    af[mi] = *(const bf16x8*)(As + r * 64 + 8 * (c ^ (r & 7)));
                }
#pragma unroll
                for (int ni = 0; ni < 4; ++ni) {
                    const int n = wc * 64 + ni * 16 + (lane & 15);
                    const int c = ks * 4 + (lane >> 4);
                    bfr[ni] = *(const bf16x8*)(Bs + n * 64 + 8 * (c ^ (n & 7)));
                }
#pragma unroll
                for (int mi = 0; mi < 4; ++mi)
#pragma unroll
                    for (int ni = 0; ni < 4; ++ni)
                        acc[mi][ni] = __builtin_amdgcn_mfma_f32_16x16x32_bf16(
                            bfr[ni], af[mi], acc[mi][ni], 0, 0, 0);   // swapped: D[n][m]
            }
        }
    }

    // epilogue (swapped layout): row m = lane&15, cols n = (lane>>4)*4 + reg
#pragma unroll
    for (int mi = 0; mi < 4; ++mi) {
        const int r = row0 + wr * 64 + mi * 16 + (lane & 15);
        if (r < M) {
#pragma unroll
            for (int ni = 0; ni < 4; ++ni) {
                const int c0 = col0 + wc * 64 + ni * 16 + (lane >> 4) * 4;
                float o[4];
#pragma unroll
                for (int reg = 0; reg < 4; ++reg)
                    o[reg] = activate(acc[mi][ni][reg] + bias[c0 + reg], ACT);
                uint2 cv; cv.x = pack2(o[0], o[1]); cv.y = pack2(o[2], o[3]);
                *(uint2*)(C + (size_t)r * 256 + c0) = cv;
                if constexpr (ACCMODE == 1) {
                    *(uint2*)(Cacc + (size_t)r * 256 + c0) = cv;
                } else if constexpr (ACCMODE == 2) {
                    uint2 ov = *(const uint2*)(Cacc + (size_t)r * 256 + c0);
                    uint2 nv2;
                    nv2.x = pack2(bf2f(ov.x & 0xFFFFu) + o[0], bf2f(ov.x >> 16) + o[1]);
                    nv2.y = pack2(bf2f(ov.y & 0xFFFFu) + o[2], bf2f(ov.y >> 16) + o[3]);
                    *(uint2*)(Cacc + (size_t)r * 256 + c0) = nv2;
                }
            }
        }
    }
}

// convert 10x [256][256] fp32 weight blocks -> bf16 transposed [n][k]
__global__ void wconv_all(const float* __restrict__ W_lin, const float* __restrict__ W2,
                          const float* __restrict__ W1sg, const float* __restrict__ W2sg,
                          const float* __restrict__ Wc1, const float* __restrict__ Wc2,
                          const float* __restrict__ W3, bf16* __restrict__ out)
{
    const int b = blockIdx.x;
    const int m = b >> 8, k = b & 255, n = threadIdx.x;
    const float* src;
    switch (m) {
        case 0: src = W_lin; break;       case 1: src = W2; break;
        case 2: src = W1sg; break;        case 3: src = W2sg; break;
        case 4: src = Wc1; break;         case 5: src = Wc1 + 65536; break;
        case 6: src = Wc2; break;         case 7: src = Wc2 + 65536; break;
        case 8: src = W3; break;          default: src = W3 + 65536; break;
    }
    out[(size_t)m * 65536 + n * 256 + k] = f2bf(src[k * 256 + n]);
}

// ---------------- graph aggregation ----------------
template<bool GATHER>
__global__ void agg_x1(const bf16* __restrict__ x, const int* __restrict__ gidx,
                       const float* __restrict__ norm,
                       const int* __restrict__ rp, const int* __restrict__ ssrc,
                       const float* __restrict__ lam, bf16* __restrict__ X1, int M)
{
    int d = blockIdx.x * 4 + (threadIdx.x >> 6);
    if (d >= M) return;
    int l = threadIdx.x & 63;
    float s0 = 0.f, s1 = 0.f, s2 = 0.f, s3 = 0.f;
    int e0 = rp[d], e1 = rp[d + 1];
    for (int e = e0; e < e1; ++e) {
        int si = ssrc[e];
        float nv = norm[si];
        const bf16* xr = x + (size_t)(GATHER ? gidx[si] : si) * 256 + l * 4;
        uint2 u = *(const uint2*)xr;
        s0 += bf2f(u.x & 0xFFFFu) * nv; s1 += bf2f(u.x >> 16) * nv;
        s2 += bf2f(u.y & 0xFFFFu) * nv; s3 += bf2f(u.y >> 16) * nv;
    }
    float re = 2.0f / lam[0];
    float a = -re * norm[d];
    float b = re - 1.0f;
    const bf16* xdp = x + (size_t)(GATHER ? gidx[d] : d) * 256 + l * 4;
    uint2 xd = *(const uint2*)xdp;
    uint2 o;
    o.x = pack2(a * s0 + b * bf2f(xd.x & 0xFFFFu), a * s1 + b * bf2f(xd.x >> 16));
    o.y = pack2(a * s2 + b * bf2f(xd.y & 0xFFFFu), a * s3 + b * bf2f(xd.y >> 16));
    *(uint2*)(X1 + (size_t)d * 256 + l * 4) = o;
}

__global__ void zero_k(int* __restrict__ p, int n)
{
    int i = blockIdx.x * 256 + threadIdx.x;
    if (i < n) p[i] = 0;
}

__global__ void hist_k(const int* __restrict__ dst, int* __restrict__ deg, int E)
{
    int e = blockIdx.x * 256 + threadIdx.x;
    if (e < E) atomicAdd(&deg[dst[e]], 1);
}

// ---- parallel 3-phase exclusive scan: deg[0..M) -> rp[0..M] ----
__global__ void scan1_k(const int* __restrict__ deg, int* __restrict__ bsum, int M)
{
    __shared__ int red[256];
    int b = blockIdx.x, t = threadIdx.x;
    int base = b * 1024 + t * 4;
    int s = 0;
#pragma unroll
    for (int j = 0; j < 4; ++j) { int i = base + j; if (i < M) s += deg[i]; }
    red[t] = s; __syncthreads();
    for (int off = 128; off; off >>= 1) {
        if (t < off) red[t] += red[t + off];
        __syncthreads();
    }
    if (t == 0) bsum[b] = red[0];
}
__global__ void scan2_k(int* __restrict__ bsum, int nb, int* __restrict__ rp, int M)
{
    __shared__ int buf[256];
    int t = threadIdx.x;
    int v = (t < nb) ? bsum[t] : 0;
    buf[t] = v; __syncthreads();
    for (int off = 1; off < 256; off <<= 1) {
        int y = (t >= off) ? buf[t - off] : 0;
        __syncthreads();
        buf[t] += y;
        __syncthreads();
    }
    if (t < nb) bsum[t] = buf[t] - v;       // exclusive prefix of block sums
    if (t == 0) rp[M] = buf[255];           // total
}
__global__ void scan3_k(const int* __restrict__ deg, const int* __restrict__ bsum,
                        int* __restrict__ rp, int M)
{
    __shared__ int buf[256];
    int b = blockIdx.x, t = threadIdx.x;
    int base = b * 1024 + t * 4;
    int v0 = (base + 0 < M) ? deg[base + 0] : 0;
    int v1 = (base + 1 < M) ? deg[base + 1] : 0;
    int v2 = (base + 2 < M) ? deg[base + 2] : 0;
    int v3 = (base + 3 < M) ? deg[base + 3] : 0;
    int s = v0 + v1 + v2 + v3;
    buf[t] = s; __syncthreads();
    for (int off = 1; off < 256; off <<= 1) {
        int y = (t >= off) ? buf[t - off] : 0;
        __syncthreads();
        buf[t] += y;
        __syncthreads();
    }
    int ex = bsum[b] + buf[t] - s;
    if (base + 0 < M) rp[base + 0] = ex;
    if (base + 1 < M) rp[base + 1] = ex + v0;
    if (base + 2 < M) rp[base + 2] = ex + v0 + v1;
    if (base + 3 < M) rp[base + 3] = ex + v0 + v1 + v2;
}

__global__ void scatter_k(const int* __restrict__ src, const int* __restrict__ dst,
                          const int* __restrict__ rp, int* __restrict__ cursor,
                          int* __restrict__ out, int E)
{
    int e = blockIdx.x * 256 + threadIdx.x;
    if (e < E) {
        int d = dst[e];
        int pos = rp[d] + atomicAdd(&cursor[d], 1);
        out[pos] = src[e];
    }
}

// out[r,0:2] = leaky_relu(ACC[r,:]) @ W4 + b4 ; one wave per row
__global__ void final_k(const bf16* __restrict__ acc, const float* __restrict__ W4,
                        const float* __restrict__ b4, float* __restrict__ out, int Nn)
{
    int r = blockIdx.x * 4 + (threadIdx.x >> 6);
    if (r >= Nn) return;
    int l = threadIdx.x & 63;
    uint2 u = *(const uint2*)(acc + (size_t)r * 256 + l * 4);
    float v[4] = { bf2f(u.x & 0xFFFFu), bf2f(u.x >> 16),
                   bf2f(u.y & 0xFFFFu), bf2f(u.y >> 16) };
    float s0 = 0.f, s1 = 0.f;
#pragma unroll
    for (int j = 0; j < 4; ++j) {
        float x = v[j] > 0.f ? v[j] : LREL * v[j];
        int k = l * 4 + j;
        s0 += x * W4[k * 2 + 0];
        s1 += x * W4[k * 2 + 1];
    }
#pragma unroll
    for (int off = 32; off; off >>= 1) {
        s0 += __shfl_xor(s0, off, 64);
        s1 += __shfl_xor(s1, off, 64);
    }
    if (l == 0) {
        out[(size_t)r * 2 + 0] = s0 + b4[0];
        out[(size_t)r * 2 + 1] = s1 + b4[1];
    }
}

extern "C" void kernel_launch(void* const* d_in, const int* in_sizes, int n_in,
                              void* d_out, int out_size, void* d_ws, size_t ws_size,
                              hipStream_t stream)
{
    const float* in_feat = (const float*)d_in[0];
    const int Nn = in_sizes[0] / 256;   // 100000

    const float* W_lin = (const float*)d_in[19]; const float* b_lin = (const float*)d_in[20];
    const float* W2p   = (const float*)d_in[21]; const float* b2   = (const float*)d_in[22];
    const float* W1sg  = (const float*)d_in[23]; const float* b1sg = (const float*)d_in[24];
    const float* W2sg  = (const float*)d_in[25]; const float* b2sg = (const float*)d_in[26];
    const float* Wc1   = (const float*)d_in[27]; const float* bc1  = (const float*)d_in[28];
    const float* Wc2   = (const float*)d_in[29]; const float* bc2  = (const float*)d_in[30];
    const float* W3p   = (const float*)d_in[31]; const float* b3   = (const float*)d_in[32];
    const float* W4p   = (const float*)d_in[33]; const float* b4   = (const float*)d_in[34];

    int Mr[3], NIr[3], Er[3];
    int M_max = 0, NI_max = 0, E_max = 0;
    for (int r = 0; r < 3; ++r) {
        Mr[r]  = in_sizes[1 + 6 * r];
        NIr[r] = in_sizes[2 + 6 * r];
        Er[r]  = in_sizes[3 + 6 * r];
        if (Mr[r] > M_max)  M_max  = Mr[r];
        if (NIr[r] > NI_max) NI_max = NIr[r];
        if (Er[r] > E_max)  E_max  = Er[r];
    }

    // workspace (bf16 features), ~245 MB
    bf16* ACC = (bf16*)d_ws;                         // [Nn,256] running sum (tmp for layer0)
    bf16* H   = ACC + (size_t)Nn * 256;              // [Nn,256] current features
    bf16* S1  = H + (size_t)Nn * 256;                // [M_max,256] X1 / h02
    bf16* S2  = S1 + (size_t)M_max * 256;            // [M_max,256] h01
    bf16* S3  = S2 + (size_t)M_max * 256;            // [M_max,256] h11
    bf16* S4  = S3 + (size_t)M_max * 256;            // [NI_max,256] h12
    bf16* WTb = S4 + (size_t)NI_max * 256;           // 10 x [256][256] bf16 transposed
    int* deg    = (int*)(WTb + 10 * 65536);          // [Nn+1]
    int* cursor = deg + (Nn + 1);                    // [Nn+1]
    int* rp     = cursor + (Nn + 1);                 // [Nn+1]
    int* bsum   = rp + (Nn + 1);                     // [256]
    int* ssrc   = bsum + 256;                        // [E_max]

    bf16* WT_lin = WTb;             bf16* WT_2   = WTb + 1 * 65536;
    bf16* WT_1sg = WTb + 2 * 65536; bf16* WT_2sg = WTb + 3 * 65536;
    bf16* WT_c1a = WTb + 4 * 65536; bf16* WT_c1b = WTb + 5 * 65536;
    bf16* WT_c2a = WTb + 6 * 65536; bf16* WT_c2b = WTb + 7 * 65536;
    bf16* WT_3a  = WTb + 8 * 65536; bf16* WT_3b  = WTb + 9 * 65536;

    // grid: x = 2 col-tiles (adjacent -> A-tile L2 reuse), y = row-tiles
    auto g2 = [](int M) { return dim3(2u, (unsigned)((M + 127) / 128)); };

    // weights -> bf16 transposed (graph-safe, every call)
    wconv_all<<<2560, 256, 0, stream>>>(W_lin, W2p, W1sg, W2sg, Wc1, Wc2, W3p, WTb);

    // h = leaky(leaky(in @ W_lin + b_lin) @ W2 + b2)
    gemm_mfma<2, false, 0, false, true><<<g2(Nn), 256, 0, stream>>>(
        in_feat, nullptr, nullptr, WT_lin, nullptr, b_lin, ACC, nullptr, Nn);
    gemm_mfma<2, false, 0, false, false><<<g2(Nn), 256, 0, stream>>>(
        ACC, nullptr, nullptr, WT_2, nullptr, b2, H, nullptr, Nn);

    for (int r = 0; r < 3; ++r) {
        const int*   keep = (const int*)d_in[1 + 6 * r];
        const int*   iso  = (const int*)d_in[2 + 6 * r];
        const int*   srcA = (const int*)d_in[3 + 6 * r];
        const int*   dstA = (const int*)d_in[4 + 6 * r];
        const float* norm = (const float*)d_in[5 + 6 * r];
        const float* lam  = (const float*)d_in[6 + 6 * r];
        const int M  = Mr[r];
        const int NI = NIr[r];
        const int E  = Er[r];
        const int nb = (M + 1023) / 1024;

        // CSR build (src ids grouped by dst)
        zero_k<<<(2 * (Nn + 1) + 255) / 256, 256, 0, stream>>>(deg, 2 * (Nn + 1));
        hist_k<<<(E + 255) / 256, 256, 0, stream>>>(dstA, deg, E);
        scan1_k<<<nb, 256, 0, stream>>>(deg, bsum, M);
        scan2_k<<<1, 256, 0, stream>>>(bsum, nb, rp, M);
        scan3_k<<<nb, 256, 0, stream>>>(deg, bsum, rp, M);
        scatter_k<<<(E + 255) / 256, 256, 0, stream>>>(srcA, dstA, rp, cursor, ssrc, E);

        // cheb1: h01 = relu([H[keep], X1] @ Wc1 + bc1)
        agg_x1<true><<<(M + 3) / 4, 256, 0, stream>>>(H, keep, norm, rp, ssrc, lam, S1, M);
        gemm_mfma<1, true, 0, true, false><<<g2(M), 256, 0, stream>>>(
            H, keep, S1, WT_c1a, WT_c1b, bc1, S2, nullptr, M);
        // cheb2: h11 = relu([h01, X1'] @ Wc2 + bc2)
        agg_x1<false><<<(M + 3) / 4, 256, 0, stream>>>(S2, nullptr, norm, rp, ssrc, lam, S1, M);
        gemm_mfma<1, true, 0, false, false><<<g2(M), 256, 0, stream>>>(
            S2, nullptr, S1, WT_c2a, WT_c2b, bc2, S3, nullptr, M);

        // iso branch: h02 = H[iso]@W1sg + b1sg ; h12 = h02@W2sg + b2sg
        gemm_mfma<0, false, 0, true, false><<<g2(NI), 256, 0, stream>>>(
            H, iso, nullptr, WT_1sg, nullptr, b1sg, S1, nullptr, NI);
        gemm_mfma<0, false, 0, false, false><<<g2(NI), 256, 0, stream>>>(
            S1, nullptr, nullptr, WT_2sg, nullptr, b2sg, S4, nullptr, NI);

        // block output overwrites H (iso rows first; all old-H reads are done)
        if (r == 0) {
            gemm_mfma<0, true, 1, false, false><<<g2(NI), 256, 0, stream>>>(
                S1, nullptr, S4, WT_3a, WT_3b, b3,
                H + (size_t)M * 256, ACC + (size_t)M * 256, NI);
            gemm_mfma<0, true, 1, false, false><<<g2(M), 256, 0, stream>>>(
                S2, nullptr, S3, WT_3a, WT_3b, b3, H, ACC, M);
        } else {
            gemm_mfma<0, true, 2, false, false><<<g2(NI), 256, 0, stream>>>(
                S1, nullptr, S4, WT_3a, WT_3b, b3,
                H + (size_t)M * 256, ACC + (size_t)M * 256, NI);
            gemm_mfma<0, true, 2, false, false><<<g2(M), 256, 0, stream>>>(
                S2, nullptr, S3, WT_3a, WT_3b, b3, H, ACC, M);
        }
    }

    final_k<<<(Nn + 3) / 4, 256, 0, stream>>>(ACC, W4p, b4, (float*)d_out, Nn);
}

// Round 8
// 2476.060 us; speedup vs baseline: 1.9063x; 1.0404x over previous
//
#include <hip/hip_runtime.h>
#include <cstddef>

typedef unsigned short bf16;
typedef short bf16x8 __attribute__((ext_vector_type(8)));
typedef float f32x4 __attribute__((ext_vector_type(4)));
#define LREL 0.01f

__device__ __forceinline__ float bf2f(unsigned int u) {
    union { unsigned int i; float f; } c; c.i = u << 16; return c.f;
}
__device__ __forceinline__ bf16 f2bf(float f) {
    union { unsigned int i; float f; } c; c.f = f;
    return (bf16)((c.i + 0x7FFFu + ((c.i >> 16) & 1u)) >> 16);   // RNE (finite)
}
__device__ __forceinline__ unsigned int pack2(float a, float b) {
    return (unsigned int)f2bf(a) | ((unsigned int)f2bf(b) << 16);
}
__device__ __forceinline__ float activate(float v, int ACT) {
    if (ACT == 1) return v > 0.f ? v : 0.f;
    if (ACT == 2) return v > 0.f ? v : LREL * v;
    return v;
}

// ---------------- MFMA GEMM, 128x256 tile (full N per block) ----------------
// C[M,256](bf16) = act(A1@W1 (+ A2@W2) + bias); optional running-sum into Cacc.
// A: bf16 [*,256] (fp32 when AFP32). WT*: bf16 [256 n][256 k]. GATHER: A1 row
// r = A1[rows1[r]]. 1-D grid over 128-row tiles: A is fetched ONCE (R7 showed
// FETCH = 2x in_feat from the 2-col-tile grid). BK=64, 4 waves, each wave owns
// 64 cols x 128 rows (acc[8][4]); swapped mfma(B,A) -> lane owns 4 consecutive
// cols of one row -> 8B coalesced stores; 4 waves cover the full 512B row.
// LDS: As 16KB + Bs 32KB = 48KB; 16B chunk c of row r at slot c^(r&7)
// (B-frag reads stay exactly 2-way bank aliasing = free).
template<int ACT, bool DUAL, int ACCMODE, bool GATHER, bool AFP32>
__global__ __launch_bounds__(256) void gemm_mfma(
    const void* __restrict__ A1v, const int* __restrict__ rows1,
    const bf16* __restrict__ A2,
    const bf16* __restrict__ WT1, const bf16* __restrict__ WT2,
    const float* __restrict__ bias,
    bf16* __restrict__ C, bf16* __restrict__ Cacc, int M)
{
    __shared__ bf16 As[128 * 64];
    __shared__ bf16 Bs[256 * 64];
    const int tid  = threadIdx.x;
    const int lane = tid & 63;
    const int wv   = tid >> 6;           // wave = col-quarter (64 cols)
    const int row0 = blockIdx.x * 128;

    f32x4 acc[8][4];
#pragma unroll
    for (int mi = 0; mi < 8; ++mi)
#pragma unroll
        for (int ni = 0; ni < 4; ++ni)
#pragma unroll
            for (int e = 0; e < 4; ++e) acc[mi][ni][e] = 0.f;

    // A staging: thread stages row (tid&127), k-half (tid>>7) -> 4 x 16B chunks
    const int ar = tid & 127;
    const int ah = tid >> 7;
    const int arow = min(row0 + ar, M - 1);
    const size_t aoff1 = (size_t)(GATHER ? rows1[arow] : arow) * 256;
    const size_t aoff2 = (size_t)arow * 256;

    const int nparts = DUAL ? 2 : 1;
    for (int part = 0; part < nparts; ++part) {
        const bf16* __restrict__ WT = (part == 0) ? WT1 : WT2;
        for (int kt = 0; kt < 256; kt += 64) {
            uint4 areg[4], breg[8];
#pragma unroll
            for (int cc = 0; cc < 4; ++cc) {
                const int c = ah * 4 + cc;
                if (part == 0) {
                    if constexpr (AFP32) {
                        const float* p = (const float*)A1v + aoff1 + kt + c * 8;
                        float4 f0 = *(const float4*)p;
                        float4 f1 = *(const float4*)(p + 4);
                        areg[cc].x = pack2(f0.x, f0.y); areg[cc].y = pack2(f0.z, f0.w);
                        areg[cc].z = pack2(f1.x, f1.y); areg[cc].w = pack2(f1.z, f1.w);
                    } else {
                        areg[cc] = *(const uint4*)((const bf16*)A1v + aoff1 + kt + c * 8);
                    }
                } else {
                    areg[cc] = *(const uint4*)(A2 + aoff2 + kt + c * 8);
                }
            }
            // B staging: thread stages WT row n = tid, 8 x 16B chunks (128B)
#pragma unroll
            for (int cc = 0; cc < 8; ++cc)
                breg[cc] = *(const uint4*)(WT + (size_t)tid * 256 + kt + cc * 8);
            __syncthreads();            // previous compute done before overwrite
#pragma unroll
            for (int cc = 0; cc < 4; ++cc) {
                const int c = ah * 4 + cc;
                *(uint4*)(As + ar * 64 + 8 * (c ^ (ar & 7))) = areg[cc];
            }
#pragma unroll
            for (int cc = 0; cc < 8; ++cc)
                *(uint4*)(Bs + tid * 64 + 8 * (cc ^ (tid & 7))) = breg[cc];
            __syncthreads();
#pragma unroll
            for (int ks = 0; ks < 2; ++ks) {
                const int c = ks * 4 + (lane >> 4);
                bf16x8 bfr[4];
#pragma unroll
                for (int ni = 0; ni < 4; ++ni) {
                    const int n = wv * 64 + ni * 16 + (lane & 15);
                    bfr[ni] = *(const bf16x8*)(Bs + n * 64 + 8 * (c ^ (n & 7)));
                }
#pragma unroll
                for (int mi = 0; mi < 8; ++mi) {
                    const int r = mi * 16 + (lane & 15);
                    bf16x8 af = *(const bf16x8*)(As + r * 64 + 8 * (c ^ (r & 7)));
#pragma unroll
                    for (int ni = 0; ni < 4; ++ni)
                        acc[mi][ni] = __builtin_amdgcn_mfma_f32_16x16x32_bf16(
                            bfr[ni], af, acc[mi][ni], 0, 0, 0);   // swapped: D[n][m]
                }
            }
        }
    }

    // epilogue (swapped layout): row m = lane&15, cols n = (lane>>4)*4 + reg
#pragma unroll
    for (int mi = 0; mi < 8; ++mi) {
        const int r = row0 + mi * 16 + (lane & 15);
        if (r < M) {
#pragma unroll
            for (int ni = 0; ni < 4; ++ni) {
                const int c0 = wv * 64 + ni * 16 + (lane >> 4) * 4;
                float o[4];
#pragma unroll
                for (int reg = 0; reg < 4; ++reg)
                    o[reg] = activate(acc[mi][ni][reg] + bias[c0 + reg], ACT);
                uint2 cv; cv.x = pack2(o[0], o[1]); cv.y = pack2(o[2], o[3]);
                *(uint2*)(C + (size_t)r * 256 + c0) = cv;
                if constexpr (ACCMODE == 1) {
                    *(uint2*)(Cacc + (size_t)r * 256 + c0) = cv;
                } else if constexpr (ACCMODE == 2) {
                    uint2 ov = *(const uint2*)(Cacc + (size_t)r * 256 + c0);
                    uint2 nv2;
                    nv2.x = pack2(bf2f(ov.x & 0xFFFFu) + o[0], bf2f(ov.x >> 16) + o[1]);
                    nv2.y = pack2(bf2f(ov.y & 0xFFFFu) + o[2], bf2f(ov.y >> 16) + o[3]);
                    *(uint2*)(Cacc + (size_t)r * 256 + c0) = nv2;
                }
            }
        }
    }
}

// convert 10x [256][256] fp32 weight blocks -> bf16 transposed [n][k]
__global__ void wconv_all(const float* __restrict__ W_lin, const float* __restrict__ W2,
                          const float* __restrict__ W1sg, const float* __restrict__ W2sg,
                          const float* __restrict__ Wc1, const float* __restrict__ Wc2,
                          const float* __restrict__ W3, bf16* __restrict__ out)
{
    const int b = blockIdx.x;
    const int m = b >> 8, k = b & 255, n = threadIdx.x;
    const float* src;
    switch (m) {
        case 0: src = W_lin; break;       case 1: src = W2; break;
        case 2: src = W1sg; break;        case 3: src = W2sg; break;
        case 4: src = Wc1; break;         case 5: src = Wc1 + 65536; break;
        case 6: src = Wc2; break;         case 7: src = Wc2 + 65536; break;
        case 8: src = W3; break;          default: src = W3 + 65536; break;
    }
    out[(size_t)m * 65536 + n * 256 + k] = f2bf(src[k * 256 + n]);
}

// ---------------- graph aggregation ----------------
template<bool GATHER>
__global__ void agg_x1(const bf16* __restrict__ x, const int* __restrict__ gidx,
                       const float* __restrict__ norm,
                       const int* __restrict__ rp, const int* __restrict__ ssrc,
                       const float* __restrict__ lam, bf16* __restrict__ X1, int M)
{
    int d = blockIdx.x * 4 + (threadIdx.x >> 6);
    if (d >= M) return;
    int l = threadIdx.x & 63;
    float s0 = 0.f, s1 = 0.f, s2 = 0.f, s3 = 0.f;
    int e0 = rp[d], e1 = rp[d + 1];
    for (int e = e0; e < e1; ++e) {
        int si = ssrc[e];
        float nv = norm[si];
        const bf16* xr = x + (size_t)(GATHER ? gidx[si] : si) * 256 + l * 4;
        uint2 u = *(const uint2*)xr;
        s0 += bf2f(u.x & 0xFFFFu) * nv; s1 += bf2f(u.x >> 16) * nv;
        s2 += bf2f(u.y & 0xFFFFu) * nv; s3 += bf2f(u.y >> 16) * nv;
    }
    float re = 2.0f / lam[0];
    float a = -re * norm[d];
    float b = re - 1.0f;
    const bf16* xdp = x + (size_t)(GATHER ? gidx[d] : d) * 256 + l * 4;
    uint2 xd = *(const uint2*)xdp;
    uint2 o;
    o.x = pack2(a * s0 + b * bf2f(xd.x & 0xFFFFu), a * s1 + b * bf2f(xd.x >> 16));
    o.y = pack2(a * s2 + b * bf2f(xd.y & 0xFFFFu), a * s3 + b * bf2f(xd.y >> 16));
    *(uint2*)(X1 + (size_t)d * 256 + l * 4) = o;
}

__global__ void zero_k(int* __restrict__ p, int n)
{
    int i = blockIdx.x * 256 + threadIdx.x;
    if (i < n) p[i] = 0;
}

__global__ void hist_k(const int* __restrict__ dst, int* __restrict__ deg, int E)
{
    int e = blockIdx.x * 256 + threadIdx.x;
    if (e < E) atomicAdd(&deg[dst[e]], 1);
}

// ---- parallel 3-phase exclusive scan: deg[0..M) -> rp[0..M] ----
__global__ void scan1_k(const int* __restrict__ deg, int* __restrict__ bsum, int M)
{
    __shared__ int red[256];
    int b = blockIdx.x, t = threadIdx.x;
    int base = b * 1024 + t * 4;
    int s = 0;
#pragma unroll
    for (int j = 0; j < 4; ++j) { int i = base + j; if (i < M) s += deg[i]; }
    red[t] = s; __syncthreads();
    for (int off = 128; off; off >>= 1) {
        if (t < off) red[t] += red[t + off];
        __syncthreads();
    }
    if (t == 0) bsum[b] = red[0];
}
__global__ void scan2_k(int* __restrict__ bsum, int nb, int* __restrict__ rp, int M)
{
    __shared__ int buf[256];
    int t = threadIdx.x;
    int v = (t < nb) ? bsum[t] : 0;
    buf[t] = v; __syncthreads();
    for (int off = 1; off < 256; off <<= 1) {
        int y = (t >= off) ? buf[t - off] : 0;
        __syncthreads();
        buf[t] += y;
        __syncthreads();
    }
    if (t < nb) bsum[t] = buf[t] - v;       // exclusive prefix of block sums
    if (t == 0) rp[M] = buf[255];           // total
}
__global__ void scan3_k(const int* __restrict__ deg, const int* __restrict__ bsum,
                        int* __restrict__ rp, int M)
{
    __shared__ int buf[256];
    int b = blockIdx.x, t = threadIdx.x;
    int base = b * 1024 + t * 4;
    int v0 = (base + 0 < M) ? deg[base + 0] : 0;
    int v1 = (base + 1 < M) ? deg[base + 1] : 0;
    int v2 = (base + 2 < M) ? deg[base + 2] : 0;
    int v3 = (base + 3 < M) ? deg[base + 3] : 0;
    int s = v0 + v1 + v2 + v3;
    buf[t] = s; __syncthreads();
    for (int off = 1; off < 256; off <<= 1) {
        int y = (t >= off) ? buf[t - off] : 0;
        __syncthreads();
        buf[t] += y;
        __syncthreads();
    }
    int ex = bsum[b] + buf[t] - s;
    if (base + 0 < M) rp[base + 0] = ex;
    if (base + 1 < M) rp[base + 1] = ex + v0;
    if (base + 2 < M) rp[base + 2] = ex + v0 + v1;
    if (base + 3 < M) rp[base + 3] = ex + v0 + v1 + v2;
}

__global__ void scatter_k(const int* __restrict__ src, const int* __restrict__ dst,
                          const int* __restrict__ rp, int* __restrict__ cursor,
                          int* __restrict__ out, int E)
{
    int e = blockIdx.x * 256 + threadIdx.x;
    if (e < E) {
        int d = dst[e];
        int pos = rp[d] + atomicAdd(&cursor[d], 1);
        out[pos] = src[e];
    }
}

// out[r,0:2] = leaky_relu(ACC[r,:]) @ W4 + b4 ; one wave per row
__global__ void final_k(const bf16* __restrict__ acc, const float* __restrict__ W4,
                        const float* __restrict__ b4, float* __restrict__ out, int Nn)
{
    int r = blockIdx.x * 4 + (threadIdx.x >> 6);
    if (r >= Nn) return;
    int l = threadIdx.x & 63;
    uint2 u = *(const uint2*)(acc + (size_t)r * 256 + l * 4);
    float v[4] = { bf2f(u.x & 0xFFFFu), bf2f(u.x >> 16),
                   bf2f(u.y & 0xFFFFu), bf2f(u.y >> 16) };
    float s0 = 0.f, s1 = 0.f;
#pragma unroll
    for (int j = 0; j < 4; ++j) {
        float x = v[j] > 0.f ? v[j] : LREL * v[j];
        int k = l * 4 + j;
        s0 += x * W4[k * 2 + 0];
        s1 += x * W4[k * 2 + 1];
    }
#pragma unroll
    for (int off = 32; off; off >>= 1) {
        s0 += __shfl_xor(s0, off, 64);
        s1 += __shfl_xor(s1, off, 64);
    }
    if (l == 0) {
        out[(size_t)r * 2 + 0] = s0 + b4[0];
        out[(size_t)r * 2 + 1] = s1 + b4[1];
    }
}

extern "C" void kernel_launch(void* const* d_in, const int* in_sizes, int n_in,
                              void* d_out, int out_size, void* d_ws, size_t ws_size,
                              hipStream_t stream)
{
    const float* in_feat = (const float*)d_in[0];
    const int Nn = in_sizes[0] / 256;   // 100000

    const float* W_lin = (const float*)d_in[19]; const float* b_lin = (const float*)d_in[20];
    const float* W2p   = (const float*)d_in[21]; const float* b2   = (const float*)d_in[22];
    const float* W1sg  = (const float*)d_in[23]; const float* b1sg = (const float*)d_in[24];
    const float* W2sg  = (const float*)d_in[25]; const float* b2sg = (const float*)d_in[26];
    const float* Wc1   = (const float*)d_in[27]; const float* bc1  = (const float*)d_in[28];
    const float* Wc2   = (const float*)d_in[29]; const float* bc2  = (const float*)d_in[30];
    const float* W3p   = (const float*)d_in[31]; const float* b3   = (const float*)d_in[32];
    const float* W4p   = (const float*)d_in[33]; const float* b4   = (const float*)d_in[34];

    int Mr[3], NIr[3], Er[3];
    int M_max = 0, NI_max = 0, E_max = 0;
    for (int r = 0; r < 3; ++r) {
        Mr[r]  = in_sizes[1 + 6 * r];
        NIr[r] = in_sizes[2 + 6 * r];
        Er[r]  = in_sizes[3 + 6 * r];
        if (Mr[r] > M_max)  M_max  = Mr[r];
        if (NIr[r] > NI_max) NI_max = NIr[r];
        if (Er[r] > E_max)  E_max  = Er[r];
    }

    // workspace (bf16 features), ~245 MB
    bf16* ACC = (bf16*)d_ws;                         // [Nn,256] running sum (tmp for layer0)
    bf16* H   = ACC + (size_t)Nn * 256;              // [Nn,256] current features
    bf16* S1  = H + (size_t)Nn * 256;                // [M_max,256] X1 / h02
    bf16* S2  = S1 + (size_t)M_max * 256;            // [M_max,256] h01
    bf16* S3  = S2 + (size_t)M_max * 256;            // [M_max,256] h11
    bf16* S4  = S3 + (size_t)M_max * 256;            // [NI_max,256] h12
    bf16* WTb = S4 + (size_t)NI_max * 256;           // 10 x [256][256] bf16 transposed
    int* deg    = (int*)(WTb + 10 * 65536);          // [Nn+1]
    int* cursor = deg + (Nn + 1);                    // [Nn+1]
    int* rp     = cursor + (Nn + 1);                 // [Nn+1]
    int* bsum   = rp + (Nn + 1);                     // [256]
    int* ssrc   = bsum + 256;                        // [E_max]

    bf16* WT_lin = WTb;             bf16* WT_2   = WTb + 1 * 65536;
    bf16* WT_1sg = WTb + 2 * 65536; bf16* WT_2sg = WTb + 3 * 65536;
    bf16* WT_c1a = WTb + 4 * 65536; bf16* WT_c1b = WTb + 5 * 65536;
    bf16* WT_c2a = WTb + 6 * 65536; bf16* WT_c2b = WTb + 7 * 65536;
    bf16* WT_3a  = WTb + 8 * 65536; bf16* WT_3b  = WTb + 9 * 65536;

    // 1-D grid over 128-row tiles (full N=256 per block -> A read once)
    auto g1 = [](int M) { return dim3((unsigned)((M + 127) / 128)); };

    // weights -> bf16 transposed (graph-safe, every call)
    wconv_all<<<2560, 256, 0, stream>>>(W_lin, W2p, W1sg, W2sg, Wc1, Wc2, W3p, WTb);

    // h = leaky(leaky(in @ W_lin + b_lin) @ W2 + b2)
    gemm_mfma<2, false, 0, false, true><<<g1(Nn), 256, 0, stream>>>(
        in_feat, nullptr, nullptr, WT_lin, nullptr, b_lin, ACC, nullptr, Nn);
    gemm_mfma<2, false, 0, false, false><<<g1(Nn), 256, 0, stream>>>(
        ACC, nullptr, nullptr, WT_2, nullptr, b2, H, nullptr, Nn);

    for (int r = 0; r < 3; ++r) {
        const int*   keep = (const int*)d_in[1 + 6 * r];
        const int*   iso  = (const int*)d_in[2 + 6 * r];
        const int*   srcA = (const int*)d_in[3 + 6 * r];
        const int*   dstA = (const int*)d_in[4 + 6 * r];
        const float* norm = (const float*)d_in[5 + 6 * r];
        const float* lam  = (const float*)d_in[6 + 6 * r];
        const int M  = Mr[r];
        const int NI = NIr[r];
        const int E  = Er[r];
        const int nb = (M + 1023) / 1024;

        // CSR build (src ids grouped by dst)
        zero_k<<<(2 * (Nn + 1) + 255) / 256, 256, 0, stream>>>(deg, 2 * (Nn + 1));
        hist_k<<<(E + 255) / 256, 256, 0, stream>>>(dstA, deg, E);
        scan1_k<<<nb, 256, 0, stream>>>(deg, bsum, M);
        scan2_k<<<1, 256, 0, stream>>>(bsum, nb, rp, M);
        scan3_k<<<nb, 256, 0, stream>>>(deg, bsum, rp, M);
        scatter_k<<<(E + 255) / 256, 256, 0, stream>>>(srcA, dstA, rp, cursor, ssrc, E);

        // cheb1: h01 = relu([H[keep], X1] @ Wc1 + bc1)
        agg_x1<true><<<(M + 3) / 4, 256, 0, stream>>>(H, keep, norm, rp, ssrc, lam, S1, M);
        gemm_mfma<1, true, 0, true, false><<<g1(M), 256, 0, stream>>>(
            H, keep, S1, WT_c1a, WT_c1b, bc1, S2, nullptr, M);
        // cheb2: h11 = relu([h01, X1'] @ Wc2 + bc2)
        agg_x1<false><<<(M + 3) / 4, 256, 0, stream>>>(S2, nullptr, norm, rp, ssrc, lam, S1, M);
        gemm_mfma<1, true, 0, false, false><<<g1(M), 256, 0, stream>>>(
            S2, nullptr, S1, WT_c2a, WT_c2b, bc2, S3, nullptr, M);

        // iso branch: h02 = H[iso]@W1sg + b1sg ; h12 = h02@W2sg + b2sg
        gemm_mfma<0, false, 0, true, false><<<g1(NI), 256, 0, stream>>>(
            H, iso, nullptr, WT_1sg, nullptr, b1sg, S1, nullptr, NI);
        gemm_mfma<0, false, 0, false, false><<<g1(NI), 256, 0, stream>>>(
            S1, nullptr, nullptr, WT_2sg, nullptr, b2sg, S4, nullptr, NI);

        // block output overwrites H (iso rows first; all old-H reads are done)
        if (r == 0) {
            gemm_mfma<0, true, 1, false, false><<<g1(NI), 256, 0, stream>>>(
                S1, nullptr, S4, WT_3a, WT_3b, b3,
                H + (size_t)M * 256, ACC + (size_t)M * 256, NI);
            gemm_mfma<0, true, 1, false, false><<<g1(M), 256, 0, stream>>>(
                S2, nullptr, S3, WT_3a, WT_3b, b3, H, ACC, M);
        } else {
            gemm_mfma<0, true, 2, false, false><<<g1(NI), 256, 0, stream>>>(
                S1, nullptr, S4, WT_3a, WT_3b, b3,
                H + (size_t)M * 256, ACC + (size_t)M * 256, NI);
            gemm_mfma<0, true, 2, false, false><<<g1(M), 256, 0, stream>>>(
                S2, nullptr, S3, WT_3a, WT_3b, b3, H, ACC, M);
        }
    }

    final_k<<<(Nn + 3) / 4, 256, 0, stream>>>(ACC, W4p, b4, (float*)d_out, Nn);
}

// Round 10
// 2171.619 us; speedup vs baseline: 2.1735x; 1.1402x over previous
//
#include <hip/hip_runtime.h>
#include <cstddef>

typedef unsigned short bf16;
typedef short bf16x8 __attribute__((ext_vector_type(8)));
typedef float f32x4 __attribute__((ext_vector_type(4)));
#define LREL 0.01f

__device__ __forceinline__ float bf2f(unsigned int u) {
    union { unsigned int i; float f; } c; c.i = u << 16; return c.f;
}
__device__ __forceinline__ bf16 f2bf(float f) {
    union { unsigned int i; float f; } c; c.f = f;
    return (bf16)((c.i + 0x7FFFu + ((c.i >> 16) & 1u)) >> 16);   // RNE (finite)
}
__device__ __forceinline__ unsigned int pack2(float a, float b) {
    return (unsigned int)f2bf(a) | ((unsigned int)f2bf(b) << 16);
}
__device__ __forceinline__ float activate(float v, int ACT) {
    if (ACT == 1) return v > 0.f ? v : 0.f;
    if (ACT == 2) return v > 0.f ? v : LREL * v;
    return v;
}

// ---------------- MFMA GEMM, 128x256 tile, 512 threads, pipelined ----------
// C[M,256](bf16) = act(A1@W1 (+ A2@W2) + bias); optional running-sum into Cacc.
// 8 waves, each owns 32 cols x 128 rows (acc[8][2] = 64 VGPR). A read once.
// Register prefetch: step s+1's global loads issue BEFORE step s's MFMAs.
// Epilogue: acc -> LDS [16][264] transpose tile -> uint4 row-linear stores
// (fixes R8's 3x write amplification from 32B scattered segments).
// LDS chunk swizzle in As/Bs: 16B chunk c of row r at slot c^(r&7).
template<int ACT, bool DUAL, int ACCMODE, bool GATHER, bool AFP32>
__global__ __launch_bounds__(512, 4) void gemm_mfma(
    const void* __restrict__ A1v, const int* __restrict__ rows1,
    const bf16* __restrict__ A2,
    const bf16* __restrict__ WT1, const bf16* __restrict__ WT2,
    const float* __restrict__ bias,
    bf16* __restrict__ C, bf16* __restrict__ Cacc, int M)
{
    __shared__ bf16 As[128 * 64];     // 16 KB
    __shared__ bf16 Bs[256 * 64];     // 32 KB
    const int tid  = threadIdx.x;
    const int lane = tid & 63;
    const int w    = tid >> 6;        // wave 0..7 -> 32-col group
    const int row0 = blockIdx.x * 128;

    f32x4 acc[8][2];
#pragma unroll
    for (int mi = 0; mi < 8; ++mi)
#pragma unroll
        for (int ni = 0; ni < 2; ++ni)
#pragma unroll
            for (int e = 0; e < 4; ++e) acc[mi][ni][e] = 0.f;

    // staging: A row = tid&127, chunks (tid>>7)*2+{0,1}; B row = tid&255,
    // chunks (tid>>8)*4+{0..3}  (chunk = 16B = 8 bf16)
    const int ar = tid & 127;
    const int ah = tid >> 7;          // 0..3
    const int arow = min(row0 + ar, M - 1);
    const size_t aoff1 = (size_t)(GATHER ? rows1[arow] : arow) * 256;
    const size_t aoff2 = (size_t)arow * 256;
    const int bn = tid & 255;
    const int bh = tid >> 8;          // 0..1

    const int nsteps = DUAL ? 8 : 4;
    uint4 aprf[2], bprf[4];

    auto loadStep = [&](int s) {
        const int part = DUAL ? (s >> 2) : 0;
        const int kt = (s & 3) * 64;
#pragma unroll
        for (int cc = 0; cc < 2; ++cc) {
            const int c = ah * 2 + cc;
            if (part == 0) {
                if constexpr (AFP32) {
                    const float* p = (const float*)A1v + aoff1 + kt + c * 8;
                    float4 f0 = *(const float4*)p;
                    float4 f1 = *(const float4*)(p + 4);
                    aprf[cc].x = pack2(f0.x, f0.y); aprf[cc].y = pack2(f0.z, f0.w);
                    aprf[cc].z = pack2(f1.x, f1.y); aprf[cc].w = pack2(f1.z, f1.w);
                } else {
                    aprf[cc] = *(const uint4*)((const bf16*)A1v + aoff1 + kt + c * 8);
                }
            } else {
                aprf[cc] = *(const uint4*)(A2 + aoff2 + kt + c * 8);
            }
        }
        const bf16* __restrict__ WT = (DUAL && (s >> 2)) ? WT2 : WT1;
#pragma unroll
        for (int cc = 0; cc < 4; ++cc) {
            const int c = bh * 4 + cc;
            bprf[cc] = *(const uint4*)(WT + (size_t)bn * 256 + kt + c * 8);
        }
    };

    loadStep(0);
    for (int s = 0; s < nsteps; ++s) {
        __syncthreads();              // previous step's LDS reads done
#pragma unroll
        for (int cc = 0; cc < 2; ++cc) {
            const int c = ah * 2 + cc;
            *(uint4*)(As + ar * 64 + 8 * (c ^ (ar & 7))) = aprf[cc];
        }
#pragma unroll
        for (int cc = 0; cc < 4; ++cc) {
            const int c = bh * 4 + cc;
            *(uint4*)(Bs + bn * 64 + 8 * (c ^ (bn & 7))) = bprf[cc];
        }
        __syncthreads();
        if (s + 1 < nsteps) loadStep(s + 1);   // prefetch: overlaps MFMAs below
#pragma unroll
        for (int ks = 0; ks < 2; ++ks) {
            const int c = ks * 4 + (lane >> 4);
            bf16x8 bfr[2];
#pragma unroll
            for (int ni = 0; ni < 2; ++ni) {
                const int n = w * 32 + ni * 16 + (lane & 15);
                bfr[ni] = *(const bf16x8*)(Bs + n * 64 + 8 * (c ^ (n & 7)));
            }
#pragma unroll
            for (int mi = 0; mi < 8; ++mi) {
                const int r = mi * 16 + (lane & 15);
                bf16x8 af = *(const bf16x8*)(As + r * 64 + 8 * (c ^ (r & 7)));
#pragma unroll
                for (int ni = 0; ni < 2; ++ni)
                    acc[mi][ni] = __builtin_amdgcn_mfma_f32_16x16x32_bf16(
                        bfr[ni], af, acc[mi][ni], 0, 0, 0);   // swapped: D[n][m]
            }
        }
    }

    // ---- epilogue: per 16-row group, transpose via LDS, row-linear stores ----
    // swapped layout: out row m = lane&15, cols n = w*32 + ni*16 + (lane>>4)*4 + reg
    bf16* T = As;                     // [16][264] bf16 (8448 B, padded vs banks)
    const int m = lane & 15;
    const int rr = tid >> 5;          // 0..15
    const int ch = tid & 31;          // 16B chunk within 512B row
    for (int mi = 0; mi < 8; ++mi) {
        __syncthreads();              // prior T reads / main-loop As reads done
#pragma unroll
        for (int ni = 0; ni < 2; ++ni) {
            const int n0 = w * 32 + ni * 16 + (lane >> 4) * 4;
            float o0 = activate(acc[mi][ni][0] + bias[n0 + 0], ACT);
            float o1 = activate(acc[mi][ni][1] + bias[n0 + 1], ACT);
            float o2 = activate(acc[mi][ni][2] + bias[n0 + 2], ACT);
            float o3 = activate(acc[mi][ni][3] + bias[n0 + 3], ACT);
            *(unsigned int*)(T + m * 264 + n0)     = pack2(o0, o1);
            *(unsigned int*)(T + m * 264 + n0 + 2) = pack2(o2, o3);
        }
        __syncthreads();
        const int r = row0 + mi * 16 + rr;
        if (r < M) {
            uint4 v = *(const uint4*)(T + rr * 264 + ch * 8);
            *(uint4*)(C + (size_t)r * 256 + ch * 8) = v;
            if constexpr (ACCMODE == 1) {
                *(uint4*)(Cacc + (size_t)r * 256 + ch * 8) = v;
            } else if constexpr (ACCMODE == 2) {
                uint4 ov = *(const uint4*)(Cacc + (size_t)r * 256 + ch * 8);
                uint4 nv;
                nv.x = pack2(bf2f(ov.x & 0xFFFFu) + bf2f(v.x & 0xFFFFu),
                             bf2f(ov.x >> 16)     + bf2f(v.x >> 16));
                nv.y = pack2(bf2f(ov.y & 0xFFFFu) + bf2f(v.y & 0xFFFFu),
                             bf2f(ov.y >> 16)     + bf2f(v.y >> 16));
                nv.z = pack2(bf2f(ov.z & 0xFFFFu) + bf2f(v.z & 0xFFFFu),
                             bf2f(ov.z >> 16)     + bf2f(v.z >> 16));
                nv.w = pack2(bf2f(ov.w & 0xFFFFu) + bf2f(v.w & 0xFFFFu),
                             bf2f(ov.w >> 16)     + bf2f(v.w >> 16));
                *(uint4*)(Cacc + (size_t)r * 256 + ch * 8) = nv;
            }
        }
    }
}

// convert 10x [256][256] fp32 weight blocks -> bf16 transposed [n][k]
__global__ void wconv_all(const float* __restrict__ W_lin, const float* __restrict__ W2,
                          const float* __restrict__ W1sg, const float* __restrict__ W2sg,
                          const float* __restrict__ Wc1, const float* __restrict__ Wc2,
                          const float* __restrict__ W3, bf16* __restrict__ out)
{
    const int b = blockIdx.x;
    const int m = b >> 8, k = b & 255, n = threadIdx.x;
    const float* src;
    switch (m) {
        case 0: src = W_lin; break;       case 1: src = W2; break;
        case 2: src = W1sg; break;        case 3: src = W2sg; break;
        case 4: src = Wc1; break;         case 5: src = Wc1 + 65536; break;
        case 6: src = Wc2; break;         case 7: src = Wc2 + 65536; break;
        case 8: src = W3; break;          default: src = W3 + 65536; break;
    }
    out[(size_t)m * 65536 + n * 256 + k] = f2bf(src[k * 256 + n]);
}

// ---------------- graph aggregation ----------------
template<bool GATHER>
__global__ void agg_x1(const bf16* __restrict__ x, const int* __restrict__ gidx,
                       const float* __restrict__ norm,
                       const int* __restrict__ rp, const int* __restrict__ ssrc,
                       const float* __restrict__ lam, bf16* __restrict__ X1, int M)
{
    int d = blockIdx.x * 4 + (threadIdx.x >> 6);
    if (d >= M) return;
    int l = threadIdx.x & 63;
    float s0 = 0.f, s1 = 0.f, s2 = 0.f, s3 = 0.f;
    int e0 = rp[d], e1 = rp[d + 1];
    for (int e = e0; e < e1; ++e) {
        int si = ssrc[e];
        float nv = norm[si];
        const bf16* xr = x + (size_t)(GATHER ? gidx[si] : si) * 256 + l * 4;
        uint2 u = *(const uint2*)xr;
        s0 += bf2f(u.x & 0xFFFFu) * nv; s1 += bf2f(u.x >> 16) * nv;
        s2 += bf2f(u.y & 0xFFFFu) * nv; s3 += bf2f(u.y >> 16) * nv;
    }
    float re = 2.0f / lam[0];
    float a = -re * norm[d];
    float b = re - 1.0f;
    const bf16* xdp = x + (size_t)(GATHER ? gidx[d] : d) * 256 + l * 4;
    uint2 xd = *(const uint2*)xdp;
    uint2 o;
    o.x = pack2(a * s0 + b * bf2f(xd.x & 0xFFFFu), a * s1 + b * bf2f(xd.x >> 16));
    o.y = pack2(a * s2 + b * bf2f(xd.y & 0xFFFFu), a * s3 + b * bf2f(xd.y >> 16));
    *(uint2*)(X1 + (size_t)d * 256 + l * 4) = o;
}

__global__ void zero_k(int* __restrict__ p, int n)
{
    int i = blockIdx.x * 256 + threadIdx.x;
    if (i < n) p[i] = 0;
}

__global__ void hist_k(const int* __restrict__ dst, int* __restrict__ deg, int E)
{
    int e = blockIdx.x * 256 + threadIdx.x;
    if (e < E) atomicAdd(&deg[dst[e]], 1);
}

// ---- parallel 3-phase exclusive scan: deg[0..M) -> rp[0..M] ----
__global__ void scan1_k(const int* __restrict__ deg, int* __restrict__ bsum, int M)
{
    __shared__ int red[256];
    int b = blockIdx.x, t = threadIdx.x;
    int base = b * 1024 + t * 4;
    int s = 0;
#pragma unroll
    for (int j = 0; j < 4; ++j) { int i = base + j; if (i < M) s += deg[i]; }
    red[t] = s; __syncthreads();
    for (int off = 128; off; off >>= 1) {
        if (t < off) red[t] += red[t + off];
        __syncthreads();
    }
    if (t == 0) bsum[b] = red[0];
}
__global__ void scan2_k(int* __restrict__ bsum, int nb, int* __restrict__ rp, int M)
{
    __shared__ int buf[256];
    int t = threadIdx.x;
    int v = (t < nb) ? bsum[t] : 0;
    buf[t] = v; __syncthreads();
    for (int off = 1; off < 256; off <<= 1) {
        int y = (t >= off) ? buf[t - off] : 0;
        __syncthreads();
        buf[t] += y;
        __syncthreads();
    }
    if (t < nb) bsum[t] = buf[t] - v;       // exclusive prefix of block sums
    if (t == 0) rp[M] = buf[255];           // total
}
__global__ void scan3_k(const int* __restrict__ deg, const int* __restrict__ bsum,
                        int* __restrict__ rp, int M)
{
    __shared__ int buf[256];
    int b = blockIdx.x, t = threadIdx.x;
    int base = b * 1024 + t * 4;
    int v0 = (base + 0 < M) ? deg[base + 0] : 0;
    int v1 = (base + 1 < M) ? deg[base + 1] : 0;
    int v2 = (base + 2 < M) ? deg[base + 2] : 0;
    int v3 = (base + 3 < M) ? deg[base + 3] : 0;
    int s = v0 + v1 + v2 + v3;
    buf[t] = s; __syncthreads();
    for (int off = 1; off < 256; off <<= 1) {
        int y = (t >= off) ? buf[t - off] : 0;
        __syncthreads();
        buf[t] += y;
        __syncthreads();
    }
    int ex = bsum[b] + buf[t] - s;
    if (base + 0 < M) rp[base + 0] = ex;
    if (base + 1 < M) rp[base + 1] = ex + v0;
    if (base + 2 < M) rp[base + 2] = ex + v0 + v1;
    if (base + 3 < M) rp[base + 3] = ex + v0 + v1 + v2;
}

__global__ void scatter_k(const int* __restrict__ src, const int* __restrict__ dst,
                          const int* __restrict__ rp, int* __restrict__ cursor,
                          int* __restrict__ out, int E)
{
    int e = blockIdx.x * 256 + threadIdx.x;
    if (e < E) {
        int d = dst[e];
        int pos = rp[d] + atomicAdd(&cursor[d], 1);
        out[pos] = src[e];
    }
}

// out[r,0:2] = leaky_relu(ACC[r,:]) @ W4 + b4 ; one wave per row
__global__ void final_k(const bf16* __restrict__ acc, const float* __restrict__ W4,
                        const float* __restrict__ b4, float* __restrict__ out, int Nn)
{
    int r = blockIdx.x * 4 + (threadIdx.x >> 6);
    if (r >= Nn) return;
    int l = threadIdx.x & 63;
    uint2 u = *(const uint2*)(acc + (size_t)r * 256 + l * 4);
    float v[4] = { bf2f(u.x & 0xFFFFu), bf2f(u.x >> 16),
                   bf2f(u.y & 0xFFFFu), bf2f(u.y >> 16) };
    float s0 = 0.f, s1 = 0.f;
#pragma unroll
    for (int j = 0; j < 4; ++j) {
        float x = v[j] > 0.f ? v[j] : LREL * v[j];
        int k = l * 4 + j;
        s0 += x * W4[k * 2 + 0];
        s1 += x * W4[k * 2 + 1];
    }
#pragma unroll
    for (int off = 32; off; off >>= 1) {
        s0 += __shfl_xor(s0, off, 64);
        s1 += __shfl_xor(s1, off, 64);
    }
    if (l == 0) {
        out[(size_t)r * 2 + 0] = s0 + b4[0];
        out[(size_t)r * 2 + 1] = s1 + b4[1];
    }
}

extern "C" void kernel_launch(void* const* d_in, const int* in_sizes, int n_in,
                              void* d_out, int out_size, void* d_ws, size_t ws_size,
                              hipStream_t stream)
{
    const float* in_feat = (const float*)d_in[0];
    const int Nn = in_sizes[0] / 256;   // 100000

    const float* W_lin = (const float*)d_in[19]; const float* b_lin = (const float*)d_in[20];
    const float* W2p   = (const float*)d_in[21]; const float* b2   = (const float*)d_in[22];
    const float* W1sg  = (const float*)d_in[23]; const float* b1sg = (const float*)d_in[24];
    const float* W2sg  = (const float*)d_in[25]; const float* b2sg = (const float*)d_in[26];
    const float* Wc1   = (const float*)d_in[27]; const float* bc1  = (const float*)d_in[28];
    const float* Wc2   = (const float*)d_in[29]; const float* bc2  = (const float*)d_in[30];
    const float* W3p   = (const float*)d_in[31]; const float* b3   = (const float*)d_in[32];
    const float* W4p   = (const float*)d_in[33]; const float* b4   = (const float*)d_in[34];

    int Mr[3], NIr[3], Er[3];
    int M_max = 0, NI_max = 0, E_max = 0;
    for (int r = 0; r < 3; ++r) {
        Mr[r]  = in_sizes[1 + 6 * r];
        NIr[r] = in_sizes[2 + 6 * r];
        Er[r]  = in_sizes[3 + 6 * r];
        if (Mr[r] > M_max)  M_max  = Mr[r];
        if (NIr[r] > NI_max) NI_max = NIr[r];
        if (Er[r] > E_max)  E_max  = Er[r];
    }

    // workspace (bf16 features), ~245 MB
    bf16* ACC = (bf16*)d_ws;                         // [Nn,256] running sum (tmp for layer0)
    bf16* H   = ACC + (size_t)Nn * 256;              // [Nn,256] current features
    bf16* S1  = H + (size_t)Nn * 256;                // [M_max,256] X1 / h02
    bf16* S2  = S1 + (size_t)M_max * 256;            // [M_max,256] h01
    bf16* S3  = S2 + (size_t)M_max * 256;            // [M_max,256] h11
    bf16* S4  = S3 + (size_t)M_max * 256;            // [NI_max,256] h12
    bf16* WTb = S4 + (size_t)NI_max * 256;           // 10 x [256][256] bf16 transposed
    int* deg    = (int*)(WTb + 10 * 65536);          // [Nn+1]
    int* cursor = deg + (Nn + 1);                    // [Nn+1]
    int* rp     = cursor + (Nn + 1);                 // [Nn+1]
    int* bsum   = rp + (Nn + 1);                     // [256]
    int* ssrc   = bsum + 256;                        // [E_max]

    bf16* WT_lin = WTb;             bf16* WT_2   = WTb + 1 * 65536;
    bf16* WT_1sg = WTb + 2 * 65536; bf16* WT_2sg = WTb + 3 * 65536;
    bf16* WT_c1a = WTb + 4 * 65536; bf16* WT_c1b = WTb + 5 * 65536;
    bf16* WT_c2a = WTb + 6 * 65536; bf16* WT_c2b = WTb + 7 * 65536;
    bf16* WT_3a  = WTb + 8 * 65536; bf16* WT_3b  = WTb + 9 * 65536;

    // 1-D grid over 128-row tiles (full N=256 per block -> A read once)
    auto g1 = [](int M) { return dim3((unsigned)((M + 127) / 128)); };

    // weights -> bf16 transposed (graph-safe, every call)
    wconv_all<<<2560, 256, 0, stream>>>(W_lin, W2p, W1sg, W2sg, Wc1, Wc2, W3p, WTb);

    // h = leaky(leaky(in @ W_lin + b_lin) @ W2 + b2)
    gemm_mfma<2, false, 0, false, true><<<g1(Nn), 512, 0, stream>>>(
        in_feat, nullptr, nullptr, WT_lin, nullptr, b_lin, ACC, nullptr, Nn);
    gemm_mfma<2, false, 0, false, false><<<g1(Nn), 512, 0, stream>>>(
        ACC, nullptr, nullptr, WT_2, nullptr, b2, H, nullptr, Nn);

    for (int r = 0; r < 3; ++r) {
        const int*   keep = (const int*)d_in[1 + 6 * r];
        const int*   iso  = (const int*)d_in[2 + 6 * r];
        const int*   srcA = (const int*)d_in[3 + 6 * r];
        const int*   dstA = (const int*)d_in[4 + 6 * r];
        const float* norm = (const float*)d_in[5 + 6 * r];
        const float* lam  = (const float*)d_in[6 + 6 * r];
        const int M  = Mr[r];
        const int NI = NIr[r];
        const int E  = Er[r];
        const int nb = (M + 1023) / 1024;

        // CSR build (src ids grouped by dst)
        zero_k<<<(2 * (Nn + 1) + 255) / 256, 256, 0, stream>>>(deg, 2 * (Nn + 1));
        hist_k<<<(E + 255) / 256, 256, 0, stream>>>(dstA, deg, E);
        scan1_k<<<nb, 256, 0, stream>>>(deg, bsum, M);
        scan2_k<<<1, 256, 0, stream>>>(bsum, nb, rp, M);
        scan3_k<<<nb, 256, 0, stream>>>(deg, bsum, rp, M);
        scatter_k<<<(E + 255) / 256, 256, 0, stream>>>(srcA, dstA, rp, cursor, ssrc, E);

        // cheb1: h01 = relu([H[keep], X1] @ Wc1 + bc1)
        agg_x1<true><<<(M + 3) / 4, 256, 0, stream>>>(H, keep, norm, rp, ssrc, lam, S1, M);
        gemm_mfma<1, true, 0, true, false><<<g1(M), 512, 0, stream>>>(
            H, keep, S1, WT_c1a, WT_c1b, bc1, S2, nullptr, M);
        // cheb2: h11 = relu([h01, X1'] @ Wc2 + bc2)
        agg_x1<false><<<(M + 3) / 4, 256, 0, stream>>>(S2, nullptr, norm, rp, ssrc, lam, S1, M);
        gemm_mfma<1, true, 0, false, false><<<g1(M), 512, 0, stream>>>(
            S2, nullptr, S1, WT_c2a, WT_c2b, bc2, S3, nullptr, M);

        // iso branch: h02 = H[iso]@W1sg + b1sg ; h12 = h02@W2sg + b2sg
        gemm_mfma<0, false, 0, true, false><<<g1(NI), 512, 0, stream>>>(
            H, iso, nullptr, WT_1sg, nullptr, b1sg, S1, nullptr, NI);
        gemm_mfma<0, false, 0, false, false><<<g1(NI), 512, 0, stream>>>(
            S1, nullptr, nullptr, WT_2sg, nullptr, b2sg, S4, nullptr, NI);

        // block output overwrites H (iso rows first; all old-H reads are done)
        if (r == 0) {
            gemm_mfma<0, true, 1, false, false><<<g1(NI), 512, 0, stream>>>(
                S1, nullptr, S4, WT_3a, WT_3b, b3,
                H + (size_t)M * 256, ACC + (size_t)M * 256, NI);
            gemm_mfma<0, true, 1, false, false><<<g1(M), 512, 0, stream>>>(
                S2, nullptr, S3, WT_3a, WT_3b, b3, H, ACC, M);
        } else {
            gemm_mfma<0, true, 2, false, false><<<g1(NI), 512, 0, stream>>>(
                S1, nullptr, S4, WT_3a, WT_3b, b3,
                H + (size_t)M * 256, ACC + (size_t)M * 256, NI);
            gemm_mfma<0, true, 2, false, false><<<g1(M), 512, 0, stream>>>(
                S2, nullptr, S3, WT_3a, WT_3b, b3, H, ACC, M);
        }
    }

    final_k<<<(Nn + 3) / 4, 256, 0, stream>>>(ACC, W4p, b4, (float*)d_out, Nn);
}